// Round 3
// baseline (2067.915 us; speedup 1.0000x reference)
//
#include <hip/hip_runtime.h>

#define HDIM 256

typedef __attribute__((ext_vector_type(8))) short short8;
typedef __attribute__((ext_vector_type(4))) float f32x4;

__device__ __forceinline__ unsigned short f2bf(float f) {
    unsigned int u = __float_as_uint(f);
    u += 0x7FFF + ((u >> 16) & 1);   // round-to-nearest-even
    return (unsigned short)(u >> 16);
}

// ---------------- CSR build ----------------

__global__ void k_zero_int(int* p, int n) {
    int i = blockIdx.x * blockDim.x + threadIdx.x;
    if (i < n) p[i] = 0;
}

__global__ void k_hist(const int* __restrict__ src, const int* __restrict__ dst,
                       int E, int* __restrict__ deg) {
    int e = blockIdx.x * blockDim.x + threadIdx.x;
    if (e >= E) return;
    atomicAdd(&deg[dst[e]], 1);
    atomicAdd(&deg[src[e]], 1);
}

__global__ void k_scan_partial(const int* __restrict__ deg, int* __restrict__ rp,
                               int* __restrict__ bsum, int n) {
    __shared__ int sd[256];
    int t = threadIdx.x;
    int base = blockIdx.x * 1024 + t * 4;
    int v[4]; int tsum = 0;
    #pragma unroll
    for (int k = 0; k < 4; k++) { v[k] = (base + k < n) ? deg[base + k] : 0; tsum += v[k]; }
    sd[t] = tsum; __syncthreads();
    for (int off = 1; off < 256; off <<= 1) {
        int x = (t >= off) ? sd[t - off] : 0;
        __syncthreads();
        sd[t] += x;
        __syncthreads();
    }
    int run = sd[t] - tsum;
    if (t == 255) bsum[blockIdx.x] = sd[255];
    #pragma unroll
    for (int k = 0; k < 4; k++) { if (base + k < n) rp[base + k] = run; run += v[k]; }
}

__global__ void k_scan_bsum(int* __restrict__ bsum, int nb) {
    __shared__ int sd[256];
    int t = threadIdx.x;
    int base = t * 4;
    int v[4]; int tsum = 0;
    #pragma unroll
    for (int k = 0; k < 4; k++) { v[k] = (base + k < nb) ? bsum[base + k] : 0; tsum += v[k]; }
    sd[t] = tsum; __syncthreads();
    for (int off = 1; off < 256; off <<= 1) {
        int x = (t >= off) ? sd[t - off] : 0;
        __syncthreads();
        sd[t] += x;
        __syncthreads();
    }
    int run = sd[t] - tsum;
    #pragma unroll
    for (int k = 0; k < 4; k++) { if (base + k < nb) bsum[base + k] = run; run += v[k]; }
}

__global__ void k_scan_add(int* __restrict__ rp, int* __restrict__ cursor,
                           const int* __restrict__ bsum, int n, int twoE) {
    int i = blockIdx.x * blockDim.x + threadIdx.x;
    if (i < n) {
        int v = rp[i] + bsum[i >> 10];
        rp[i] = v;
        cursor[i] = v;
    }
    if (i == 0) rp[n] = twoE;
}

__global__ void k_fill(const int* __restrict__ src, const int* __restrict__ dst,
                       int E, int* __restrict__ cursor, int* __restrict__ col) {
    int e = blockIdx.x * blockDim.x + threadIdx.x;
    if (e >= E) return;
    int s = src[e], d = dst[e];
    int p = atomicAdd(&cursor[d], 1); col[p] = s;
    int q = atomicAdd(&cursor[s], 1); col[q] = d;
}

// ---------------- weight prep ----------------
// Wt[n][k] = bf16(W[k][n]), 256x256. grid=256 (k), block=256 (n)
__global__ void k_prep_w(const float* __restrict__ W, unsigned short* __restrict__ Wt) {
    int k = blockIdx.x, nn = threadIdx.x;
    Wt[nn * 256 + k] = f2bf(W[k * 256 + nn]);
}

// Wt0[n][96]: k<88 -> bf16(W0[k][n]), else 0. grid=96 (k), block=256 (n)
__global__ void k_prep_w0(const float* __restrict__ W0, unsigned short* __restrict__ Wt0) {
    int k = blockIdx.x, nn = threadIdx.x;
    Wt0[nn * 96 + k] = (k < 88) ? f2bf(W0[k * 256 + nn]) : 0;
}

// ---------------- embed + GEMM0 (88 -> 256), MFMA ----------------
// Block: 64 nodes, 256 threads = 4 waves; wave w owns cols [64w,64w+64).
// Features built as bf16 in LDS, K padded to 96; row stride 256 B (16 slots),
// XOR swizzle slot ^= (row&7).

__global__ __launch_bounds__(256) void k_embed0(
    const int* __restrict__ atom,
    const float* __restrict__ eE, const float* __restrict__ eD,
    const float* __restrict__ eV, const float* __restrict__ eC,
    const float* __restrict__ eA, const float* __restrict__ eH,
    const float* __restrict__ eHy,
    const unsigned short* __restrict__ Wt0, const float* __restrict__ b0,
    float* __restrict__ x, int n) {
    __shared__ unsigned short As[64 * 128];   // 16 KB, stride 256 B/row
    int t = threadIdx.x;
    size_t node0 = (size_t)blockIdx.x * 64;

    {
        int row = t >> 2;               // 0..63
        int ks  = (t & 3) * 24;         // 0,24,48,72
        size_t node = node0 + row;
        int a0 = 0, a1 = 0, a2 = 0, a3 = 0, a4 = 0, a5 = 0, a6 = 0;
        if (node < (size_t)n) {
            const int* a = atom + node * 7;
            a0 = a[0]; a1 = a[1]; a2 = a[2]; a3 = a[3]; a4 = a[4]; a5 = a[5]; a6 = a[6];
        }
        bool ok = node < (size_t)n;
        #pragma unroll
        for (int kk = 0; kk < 24; kk++) {
            int k = ks + kk;
            float val = 0.f;
            if (ok) {
                if (k < 64)       val = eE[a0 * 64 + k];
                else if (k < 68)  val = eD[a1 * 4 + (k - 64)];
                else if (k < 72)  val = eV[(a2 + 1) * 4 + (k - 68)];
                else if (k < 76)  val = eC[a3 * 4 + (k - 72)];
                else if (k < 80)  val = eA[a4 * 4 + (k - 76)];
                else if (k < 84)  val = eH[a5 * 4 + (k - 80)];
                else if (k < 88)  val = eHy[a6 * 4 + (k - 84)];
            }
            int boff = (k * 2) ^ ((row & 7) << 4);
            *(unsigned short*)((char*)As + row * 256 + boff) = f2bf(val);
        }
    }
    __syncthreads();

    int w  = t >> 6;
    int l  = t & 63;
    int lr = l & 15;
    int lk = l >> 4;

    f32x4 acc[4][4];
    #pragma unroll
    for (int rg = 0; rg < 4; rg++)
        #pragma unroll
        for (int cg = 0; cg < 4; cg++)
            acc[rg][cg] = (f32x4){0.f, 0.f, 0.f, 0.f};

    #pragma unroll
    for (int kt = 0; kt < 3; kt++) {
        int kbyte = kt * 64 + lk * 16;
        short8 a[4], bf[4];
        #pragma unroll
        for (int rg = 0; rg < 4; rg++) {
            int row = rg * 16 + lr;
            a[rg] = *(const short8*)((const char*)As + row * 256 + (kbyte ^ ((row & 7) << 4)));
        }
        #pragma unroll
        for (int cg = 0; cg < 4; cg++) {
            int coln = w * 64 + cg * 16 + lr;
            bf[cg] = *(const short8*)((const char*)Wt0 + coln * 192 + kbyte);
        }
        #pragma unroll
        for (int rg = 0; rg < 4; rg++)
            #pragma unroll
            for (int cg = 0; cg < 4; cg++)
                acc[rg][cg] = __builtin_amdgcn_mfma_f32_16x16x32_bf16(a[rg], bf[cg], acc[rg][cg], 0, 0, 0);
    }

    float bcol[4];
    #pragma unroll
    for (int cg = 0; cg < 4; cg++) bcol[cg] = b0[w * 64 + cg * 16 + lr];
    #pragma unroll
    for (int rg = 0; rg < 4; rg++)
        #pragma unroll
        for (int j = 0; j < 4; j++) {
            int row = rg * 16 + lk * 4 + j;
            size_t node = node0 + row;
            if (node < (size_t)n) {
                #pragma unroll
                for (int cg = 0; cg < 4; cg++)
                    x[node * HDIM + w * 64 + cg * 16 + lr] = acc[rg][cg][j] + bcol[cg];
            }
        }
}

// ---------------- fused GINE layer: gather+relu+sum -> GEMM -> LN ----------------
// Block: 64 nodes, 256 threads = 4 waves. Phase 1: wave w gathers rows
// [16w,16w+16), lane l owns float4 col-chunk l; accumulate in regs, write bf16
// LDS (XOR swizzled). Phase 2: MFMA 64x256 + bias + LayerNorm.

__global__ __launch_bounds__(256) void k_gine(
    const float* __restrict__ x, const int* __restrict__ rp,
    const int* __restrict__ col, const float* __restrict__ We,
    const float* __restrict__ be, const unsigned short* __restrict__ Wt,
    const float* __restrict__ b, const float* __restrict__ g,
    const float* __restrict__ bt, float* __restrict__ xout, int n) {
    __shared__ unsigned short As[64 * 256];     // 32 KB, stride 512 B/row
    __shared__ float psum[4][64], psq[4][64];
    __shared__ float mean_s[64], inv_s[64];

    int t = threadIdx.x;
    int w = t >> 6;
    int l = t & 63;
    size_t node0 = (size_t)blockIdx.x * 64;

    // ---- phase 1: gather + relu + segment-sum into LDS (bf16) ----
    {
        const float4* x4 = (const float4*)x;
        float4 wv = ((const float4*)We)[l];
        float4 bv = ((const float4*)be)[l];
        float cx = wv.x + bv.x, cy = wv.y + bv.y, cz = wv.z + bv.z, cw = wv.w + bv.w;
        for (int ii = 0; ii < 16; ii++) {
            int row = w * 16 + ii;
            size_t node = node0 + row;
            float4 a = make_float4(0.f, 0.f, 0.f, 0.f);
            if (node < (size_t)n) {
                a = x4[node * 64 + l];
                int p0 = rp[node], p1 = rp[node + 1];
                for (int p = p0; p < p1; p++) {
                    int s = col[p];
                    float4 v = x4[(size_t)s * 64 + l];
                    a.x += fmaxf(v.x + cx, 0.f);
                    a.y += fmaxf(v.y + cy, 0.f);
                    a.z += fmaxf(v.z + cz, 0.f);
                    a.w += fmaxf(v.w + cw, 0.f);
                }
            }
            ushort4 h;
            h.x = f2bf(a.x); h.y = f2bf(a.y); h.z = f2bf(a.z); h.w = f2bf(a.w);
            *(ushort4*)((char*)As + row * 512 + ((l << 3) ^ ((row & 7) << 4))) = h;
        }
    }
    __syncthreads();

    // ---- phase 2: MFMA ----
    int lr = l & 15;
    int lk = l >> 4;

    f32x4 acc[4][4];
    #pragma unroll
    for (int rg = 0; rg < 4; rg++)
        #pragma unroll
        for (int cg = 0; cg < 4; cg++)
            acc[rg][cg] = (f32x4){0.f, 0.f, 0.f, 0.f};

    #pragma unroll
    for (int kt = 0; kt < 8; kt++) {
        int kbyte = kt * 64 + lk * 16;
        short8 a[4], bf[4];
        #pragma unroll
        for (int rg = 0; rg < 4; rg++) {
            int row = rg * 16 + lr;
            a[rg] = *(const short8*)((const char*)As + row * 512 + (kbyte ^ ((row & 7) << 4)));
        }
        #pragma unroll
        for (int cg = 0; cg < 4; cg++) {
            int coln = w * 64 + cg * 16 + lr;
            bf[cg] = *(const short8*)((const char*)Wt + coln * 512 + kbyte);
        }
        #pragma unroll
        for (int rg = 0; rg < 4; rg++)
            #pragma unroll
            for (int cg = 0; cg < 4; cg++)
                acc[rg][cg] = __builtin_amdgcn_mfma_f32_16x16x32_bf16(a[rg], bf[cg], acc[rg][cg], 0, 0, 0);
    }

    // bias
    float bcol[4];
    #pragma unroll
    for (int cg = 0; cg < 4; cg++) bcol[cg] = b[w * 64 + cg * 16 + lr];
    #pragma unroll
    for (int rg = 0; rg < 4; rg++)
        #pragma unroll
        for (int cg = 0; cg < 4; cg++)
            #pragma unroll
            for (int j = 0; j < 4; j++) acc[rg][cg][j] += bcol[cg];

    // ---- fused LayerNorm ----
    float sv[4][4], sq[4][4];
    #pragma unroll
    for (int rg = 0; rg < 4; rg++)
        #pragma unroll
        for (int j = 0; j < 4; j++) {
            float s = 0.f, q = 0.f;
            #pragma unroll
            for (int cg = 0; cg < 4; cg++) {
                float v = acc[rg][cg][j];
                s += v; q += v * v;
            }
            sv[rg][j] = s; sq[rg][j] = q;
        }
    #pragma unroll
    for (int off = 1; off < 16; off <<= 1) {
        #pragma unroll
        for (int rg = 0; rg < 4; rg++)
            #pragma unroll
            for (int j = 0; j < 4; j++) {
                sv[rg][j] += __shfl_xor(sv[rg][j], off, 64);
                sq[rg][j] += __shfl_xor(sq[rg][j], off, 64);
            }
    }
    if (lr == 0) {
        #pragma unroll
        for (int rg = 0; rg < 4; rg++)
            #pragma unroll
            for (int j = 0; j < 4; j++) {
                int row = rg * 16 + lk * 4 + j;
                psum[w][row] = sv[rg][j];
                psq[w][row]  = sq[rg][j];
            }
    }
    __syncthreads();
    if (t < 64) {
        float s = psum[0][t] + psum[1][t] + psum[2][t] + psum[3][t];
        float q = psq[0][t] + psq[1][t] + psq[2][t] + psq[3][t];
        float m = s * (1.f / 256.f);
        float var = q * (1.f / 256.f) - m * m;
        mean_s[t] = m;
        inv_s[t]  = rsqrtf(var + 1e-5f);
    }
    __syncthreads();

    float gv[4], btv[4];
    #pragma unroll
    for (int cg = 0; cg < 4; cg++) {
        int coln = w * 64 + cg * 16 + lr;
        gv[cg] = g[coln]; btv[cg] = bt[coln];
    }
    #pragma unroll
    for (int rg = 0; rg < 4; rg++)
        #pragma unroll
        for (int j = 0; j < 4; j++) {
            int row = rg * 16 + lk * 4 + j;
            float m = mean_s[row];
            float inv = inv_s[row];
            size_t node = node0 + row;
            if (node < (size_t)n) {
                #pragma unroll
                for (int cg = 0; cg < 4; cg++)
                    xout[node * HDIM + w * 64 + cg * 16 + lr] =
                        (acc[rg][cg][j] - m) * inv * gv[cg] + btv[cg];
            }
        }
}

// ---------------- plain MFMA GEMM (final projection, no LN) ----------------

__global__ __launch_bounds__(256) void k_gemm_mfma(
    const float* __restrict__ zin, const unsigned short* __restrict__ Wt,
    const float* __restrict__ b, float* __restrict__ xout, int n) {
    __shared__ unsigned short As[64 * 256];

    int t = threadIdx.x;
    size_t node0 = (size_t)blockIdx.x * 64;

    const float4* zrow = (const float4*)(zin + node0 * HDIM);
    #pragma unroll
    for (int i = 0; i < 16; i++) {
        int g4 = i * 256 + t;
        int row = g4 >> 6;
        int c4 = g4 & 63;
        float4 v = make_float4(0.f, 0.f, 0.f, 0.f);
        if (node0 + row < (size_t)n) v = zrow[g4];
        ushort4 h;
        h.x = f2bf(v.x); h.y = f2bf(v.y); h.z = f2bf(v.z); h.w = f2bf(v.w);
        int boff = (c4 << 3) ^ ((row & 7) << 4);
        *(ushort4*)((char*)As + row * 512 + boff) = h;
    }
    __syncthreads();

    int w  = t >> 6;
    int l  = t & 63;
    int lr = l & 15;
    int lk = l >> 4;

    f32x4 acc[4][4];
    #pragma unroll
    for (int rg = 0; rg < 4; rg++)
        #pragma unroll
        for (int cg = 0; cg < 4; cg++)
            acc[rg][cg] = (f32x4){0.f, 0.f, 0.f, 0.f};

    #pragma unroll
    for (int kt = 0; kt < 8; kt++) {
        int kbyte = kt * 64 + lk * 16;
        short8 a[4], bf[4];
        #pragma unroll
        for (int rg = 0; rg < 4; rg++) {
            int row = rg * 16 + lr;
            a[rg] = *(const short8*)((const char*)As + row * 512 + (kbyte ^ ((row & 7) << 4)));
        }
        #pragma unroll
        for (int cg = 0; cg < 4; cg++) {
            int coln = w * 64 + cg * 16 + lr;
            bf[cg] = *(const short8*)((const char*)Wt + coln * 512 + kbyte);
        }
        #pragma unroll
        for (int rg = 0; rg < 4; rg++)
            #pragma unroll
            for (int cg = 0; cg < 4; cg++)
                acc[rg][cg] = __builtin_amdgcn_mfma_f32_16x16x32_bf16(a[rg], bf[cg], acc[rg][cg], 0, 0, 0);
    }

    float bcol[4];
    #pragma unroll
    for (int cg = 0; cg < 4; cg++) bcol[cg] = b[w * 64 + cg * 16 + lr];
    #pragma unroll
    for (int rg = 0; rg < 4; rg++)
        #pragma unroll
        for (int j = 0; j < 4; j++) {
            int row = rg * 16 + lk * 4 + j;
            size_t node = node0 + row;
            if (node < (size_t)n) {
                #pragma unroll
                for (int cg = 0; cg < 4; cg++)
                    xout[node * HDIM + w * 64 + cg * 16 + lr] = acc[rg][cg][j] + bcol[cg];
            }
        }
}

// ---------------- host ----------------

extern "C" void kernel_launch(void* const* d_in, const int* in_sizes, int n_in,
                              void* d_out, int out_size, void* d_ws, size_t ws_size,
                              hipStream_t stream) {
    const int*   atom = (const int*)d_in[0];
    const int*   src  = (const int*)d_in[1];
    const int*   dst  = (const int*)d_in[2];
    const float* eE   = (const float*)d_in[3];
    const float* eD   = (const float*)d_in[4];
    const float* eV   = (const float*)d_in[5];
    const float* eC   = (const float*)d_in[6];
    const float* eA   = (const float*)d_in[7];
    const float* eH   = (const float*)d_in[8];
    const float* eHy  = (const float*)d_in[9];
    const float* W0   = (const float*)d_in[10];
    const float* b0   = (const float*)d_in[11];
    const float* W1   = (const float*)d_in[12];
    const float* b1   = (const float*)d_in[13];

    const int N = in_sizes[0] / 7;
    const int E = in_sizes[1];
    const int twoE = 2 * E;

    float* x  = (float*)d_out;            // N x 256, ping
    float* xb = (float*)d_ws;             // N x 256, pong (layer outputs alternate)

    int*   rp      = (int*)(xb + (size_t)N * HDIM);      // N+1
    int*   cursor  = rp + (N + 1);
    int*   deg     = cursor + N;
    int*   col     = deg + N;                            // 2E
    int*   bsum    = col + twoE;                         // <=1024
    uintptr_t pw = (uintptr_t)(bsum + 1024);
    pw = (pw + 255) & ~(uintptr_t)255;
    unsigned short* Wt  = (unsigned short*)pw;           // 5 x 256 x 256 bf16
    unsigned short* Wt0 = Wt + (size_t)5 * 65536;        // 256 x 96 bf16

    const int nb = (N + 1023) / 1024;

    // CSR build
    k_zero_int<<<(N + 255) / 256, 256, 0, stream>>>(deg, N);
    k_hist<<<(E + 255) / 256, 256, 0, stream>>>(src, dst, E, deg);
    k_scan_partial<<<nb, 256, 0, stream>>>(deg, rp, bsum, N);
    k_scan_bsum<<<1, 256, 0, stream>>>(bsum, nb);
    k_scan_add<<<(N + 255) / 256, 256, 0, stream>>>(rp, cursor, bsum, N, twoE);
    k_fill<<<(E + 255) / 256, 256, 0, stream>>>(src, dst, E, cursor, col);

    // weight prep
    for (int L = 0; L < 4; L++) {
        const float* Wn = (const float*)d_in[14 + 6 * L + 0];
        k_prep_w<<<256, 256, 0, stream>>>(Wn, Wt + (size_t)L * 65536);
    }
    k_prep_w<<<256, 256, 0, stream>>>(W1, Wt + (size_t)4 * 65536);
    k_prep_w0<<<96, 256, 0, stream>>>(W0, Wt0);

    const int nblk64 = (N + 63) / 64;

    // embed + first GEMM (MFMA) -> x
    k_embed0<<<nblk64, 256, 0, stream>>>(atom, eE, eD, eV, eC, eA, eH, eHy,
                                         Wt0, b0, x, N);

    // 4 fused GINE layers, ping-pong x <-> xb (k_gine reads all of x, so
    // in-place is unsafe; alternate buffers instead)
    float* cur = x;
    float* nxt = xb;
    for (int L = 0; L < 4; L++) {
        const float* bn = (const float*)d_in[14 + 6 * L + 1];
        const float* We = (const float*)d_in[14 + 6 * L + 2];
        const float* be = (const float*)d_in[14 + 6 * L + 3];
        const float* g  = (const float*)d_in[14 + 6 * L + 4];
        const float* bt = (const float*)d_in[14 + 6 * L + 5];
        k_gine<<<nblk64, 256, 0, stream>>>(cur, rp, col, We, be,
                                           Wt + (size_t)L * 65536, bn, g, bt, nxt, N);
        float* tmp = cur; cur = nxt; nxt = tmp;
    }

    // final projection: cur == x after 4 swaps -> write d_out (in-place safe)
    k_gemm_mfma<<<nblk64, 256, 0, stream>>>(cur, Wt + (size_t)4 * 65536, b1,
                                            (float*)d_out, N);
}

// Round 4
// 1062.672 us; speedup vs baseline: 1.9460x; 1.9460x over previous
//
#include <hip/hip_runtime.h>

#define HDIM 256

typedef __attribute__((ext_vector_type(8))) short short8;
typedef __attribute__((ext_vector_type(4))) float f32x4;

__device__ __forceinline__ unsigned short f2bf(float f) {
    unsigned int u = __float_as_uint(f);
    u += 0x7FFF + ((u >> 16) & 1);   // round-to-nearest-even
    return (unsigned short)(u >> 16);
}
__device__ __forceinline__ float bf2f(unsigned short u) {
    return __uint_as_float(((unsigned int)u) << 16);
}

// ---------------- CSR build ----------------

__global__ void k_zero_int(int* p, int n) {
    int i = blockIdx.x * blockDim.x + threadIdx.x;
    if (i < n) p[i] = 0;
}

__global__ void k_hist(const int* __restrict__ src, const int* __restrict__ dst,
                       int E, int* __restrict__ deg) {
    int e = blockIdx.x * blockDim.x + threadIdx.x;
    if (e >= E) return;
    atomicAdd(&deg[dst[e]], 1);
    atomicAdd(&deg[src[e]], 1);
}

__global__ void k_scan_partial(const int* __restrict__ deg, int* __restrict__ rp,
                               int* __restrict__ bsum, int n) {
    __shared__ int sd[256];
    int t = threadIdx.x;
    int base = blockIdx.x * 1024 + t * 4;
    int v[4]; int tsum = 0;
    #pragma unroll
    for (int k = 0; k < 4; k++) { v[k] = (base + k < n) ? deg[base + k] : 0; tsum += v[k]; }
    sd[t] = tsum; __syncthreads();
    for (int off = 1; off < 256; off <<= 1) {
        int x = (t >= off) ? sd[t - off] : 0;
        __syncthreads();
        sd[t] += x;
        __syncthreads();
    }
    int run = sd[t] - tsum;
    if (t == 255) bsum[blockIdx.x] = sd[255];
    #pragma unroll
    for (int k = 0; k < 4; k++) { if (base + k < n) rp[base + k] = run; run += v[k]; }
}

__global__ void k_scan_bsum(int* __restrict__ bsum, int nb) {
    __shared__ int sd[256];
    int t = threadIdx.x;
    int base = t * 4;
    int v[4]; int tsum = 0;
    #pragma unroll
    for (int k = 0; k < 4; k++) { v[k] = (base + k < nb) ? bsum[base + k] : 0; tsum += v[k]; }
    sd[t] = tsum; __syncthreads();
    for (int off = 1; off < 256; off <<= 1) {
        int x = (t >= off) ? sd[t - off] : 0;
        __syncthreads();
        sd[t] += x;
        __syncthreads();
    }
    int run = sd[t] - tsum;
    #pragma unroll
    for (int k = 0; k < 4; k++) { if (base + k < nb) bsum[base + k] = run; run += v[k]; }
}

__global__ void k_scan_add(int* __restrict__ rp, int* __restrict__ cursor,
                           const int* __restrict__ bsum, int n, int twoE) {
    int i = blockIdx.x * blockDim.x + threadIdx.x;
    if (i < n) {
        int v = rp[i] + bsum[i >> 10];
        rp[i] = v;
        cursor[i] = v;
    }
    if (i == 0) rp[n] = twoE;
}

__global__ void k_fill(const int* __restrict__ src, const int* __restrict__ dst,
                       int E, int* __restrict__ cursor, int* __restrict__ col) {
    int e = blockIdx.x * blockDim.x + threadIdx.x;
    if (e >= E) return;
    int s = src[e], d = dst[e];
    int p = atomicAdd(&cursor[d], 1); col[p] = s;
    int q = atomicAdd(&cursor[s], 1); col[q] = d;
}

// ---------------- weight prep ----------------

__global__ void k_prep_w(const float* __restrict__ W, unsigned short* __restrict__ Wt) {
    int k = blockIdx.x, nn = threadIdx.x;
    Wt[nn * 256 + k] = f2bf(W[k * 256 + nn]);
}

__global__ void k_prep_w0(const float* __restrict__ W0, unsigned short* __restrict__ Wt0) {
    int k = blockIdx.x, nn = threadIdx.x;
    Wt0[nn * 96 + k] = (k < 88) ? f2bf(W0[k * 256 + nn]) : 0;
}

// ---------------- embed + GEMM0 (88 -> 256), MFMA, bf16 out ----------------

__global__ __launch_bounds__(256) void k_embed0(
    const int* __restrict__ atom,
    const float* __restrict__ eE, const float* __restrict__ eD,
    const float* __restrict__ eV, const float* __restrict__ eC,
    const float* __restrict__ eA, const float* __restrict__ eH,
    const float* __restrict__ eHy,
    const unsigned short* __restrict__ Wt0, const float* __restrict__ b0,
    unsigned short* __restrict__ x, int n) {
    __shared__ unsigned short As[64 * 256];   // 32 KB; phase1 uses 256B/row, repack 512B/row
    int t = threadIdx.x;
    size_t node0 = (size_t)blockIdx.x * 64;

    {
        int row = t >> 2;
        int ks  = (t & 3) * 24;
        size_t node = node0 + row;
        int a0 = 0, a1 = 0, a2 = 0, a3 = 0, a4 = 0, a5 = 0, a6 = 0;
        bool ok = node < (size_t)n;
        if (ok) {
            const int* a = atom + node * 7;
            a0 = a[0]; a1 = a[1]; a2 = a[2]; a3 = a[3]; a4 = a[4]; a5 = a[5]; a6 = a[6];
        }
        #pragma unroll
        for (int kk = 0; kk < 24; kk++) {
            int k = ks + kk;
            float val = 0.f;
            if (ok) {
                if (k < 64)       val = eE[a0 * 64 + k];
                else if (k < 68)  val = eD[a1 * 4 + (k - 64)];
                else if (k < 72)  val = eV[(a2 + 1) * 4 + (k - 68)];
                else if (k < 76)  val = eC[a3 * 4 + (k - 72)];
                else if (k < 80)  val = eA[a4 * 4 + (k - 76)];
                else if (k < 84)  val = eH[a5 * 4 + (k - 80)];
                else if (k < 88)  val = eHy[a6 * 4 + (k - 84)];
            }
            int boff = (k * 2) ^ ((row & 7) << 4);
            *(unsigned short*)((char*)As + row * 256 + boff) = f2bf(val);
        }
    }
    __syncthreads();

    int w  = t >> 6;
    int l  = t & 63;
    int lr = l & 15;
    int lk = l >> 4;

    f32x4 acc[4][4];
    #pragma unroll
    for (int rg = 0; rg < 4; rg++)
        #pragma unroll
        for (int cg = 0; cg < 4; cg++)
            acc[rg][cg] = (f32x4){0.f, 0.f, 0.f, 0.f};

    #pragma unroll
    for (int kt = 0; kt < 3; kt++) {
        int kbyte = kt * 64 + lk * 16;
        short8 a[4], bf[4];
        #pragma unroll
        for (int rg = 0; rg < 4; rg++) {
            int row = rg * 16 + lr;
            a[rg] = *(const short8*)((const char*)As + row * 256 + (kbyte ^ ((row & 7) << 4)));
        }
        #pragma unroll
        for (int cg = 0; cg < 4; cg++) {
            int coln = w * 64 + cg * 16 + lr;
            bf[cg] = *(const short8*)((const char*)Wt0 + coln * 192 + kbyte);
        }
        #pragma unroll
        for (int rg = 0; rg < 4; rg++)
            #pragma unroll
            for (int cg = 0; cg < 4; cg++)
                acc[rg][cg] = __builtin_amdgcn_mfma_f32_16x16x32_bf16(a[rg], bf[cg], acc[rg][cg], 0, 0, 0);
    }

    float bcol[4];
    #pragma unroll
    for (int cg = 0; cg < 4; cg++) bcol[cg] = b0[w * 64 + cg * 16 + lr];

    __syncthreads();   // As reads done; reuse for bf16 repack (512B/row swizzled)
    #pragma unroll
    for (int rg = 0; rg < 4; rg++)
        #pragma unroll
        for (int j = 0; j < 4; j++) {
            int row = rg * 16 + lk * 4 + j;
            #pragma unroll
            for (int cg = 0; cg < 4; cg++) {
                int colI = w * 64 + cg * 16 + lr;
                int byte = row * 512 + ((((colI >> 2) << 3) ^ ((row & 7) << 4)) + (colI & 3) * 2);
                *(unsigned short*)((char*)As + byte) = f2bf(acc[rg][cg][j] + bcol[cg]);
            }
        }
    __syncthreads();
    ushort4* xo = (ushort4*)(x + node0 * HDIM);
    #pragma unroll
    for (int i = 0; i < 16; i++) {
        int g4 = i * 256 + t;
        int row = g4 >> 6, c4 = g4 & 63;
        if (node0 + row < (size_t)n)
            xo[g4] = *(ushort4*)((char*)As + row * 512 + ((c4 << 3) ^ ((row & 7) << 4)));
    }
}

// ---------------- gather + relu + segment-sum (bf16 in/out, batch-4) ----------------
// one wave per node; lane l owns cols [4l,4l+4)

__global__ __launch_bounds__(256) void k_aggregate(
    const unsigned short* __restrict__ x, const int* __restrict__ rp,
    const int* __restrict__ col, const float* __restrict__ We,
    const float* __restrict__ be, unsigned short* __restrict__ z, int n) {
    int wid = threadIdx.x >> 6;
    int l   = threadIdx.x & 63;
    int node = blockIdx.x * 4 + wid;
    if (node >= n) return;
    const ushort4* x4 = (const ushort4*)x;     // 64 chunks per row
    float4 wv = ((const float4*)We)[l];
    float4 bv = ((const float4*)be)[l];
    float cx = wv.x + bv.x, cy = wv.y + bv.y, cz = wv.z + bv.z, cw = wv.w + bv.w;

    ushort4 su = x4[(size_t)node * 64 + l];
    float ax = bf2f(su.x), ay = bf2f(su.y), az = bf2f(su.z), aw = bf2f(su.w);

    int p0 = rp[node], p1 = rp[node + 1];
    int p = p0;
    for (; p + 4 <= p1; p += 4) {
        int s0 = col[p], s1 = col[p + 1], s2 = col[p + 2], s3 = col[p + 3];
        ushort4 u0 = x4[(size_t)s0 * 64 + l];
        ushort4 u1 = x4[(size_t)s1 * 64 + l];
        ushort4 u2 = x4[(size_t)s2 * 64 + l];
        ushort4 u3 = x4[(size_t)s3 * 64 + l];
        ax += fmaxf(bf2f(u0.x) + cx, 0.f); ay += fmaxf(bf2f(u0.y) + cy, 0.f);
        az += fmaxf(bf2f(u0.z) + cz, 0.f); aw += fmaxf(bf2f(u0.w) + cw, 0.f);
        ax += fmaxf(bf2f(u1.x) + cx, 0.f); ay += fmaxf(bf2f(u1.y) + cy, 0.f);
        az += fmaxf(bf2f(u1.z) + cz, 0.f); aw += fmaxf(bf2f(u1.w) + cw, 0.f);
        ax += fmaxf(bf2f(u2.x) + cx, 0.f); ay += fmaxf(bf2f(u2.y) + cy, 0.f);
        az += fmaxf(bf2f(u2.z) + cz, 0.f); aw += fmaxf(bf2f(u2.w) + cw, 0.f);
        ax += fmaxf(bf2f(u3.x) + cx, 0.f); ay += fmaxf(bf2f(u3.y) + cy, 0.f);
        az += fmaxf(bf2f(u3.z) + cz, 0.f); aw += fmaxf(bf2f(u3.w) + cw, 0.f);
    }
    for (; p < p1; p++) {
        int s = col[p];
        ushort4 u = x4[(size_t)s * 64 + l];
        ax += fmaxf(bf2f(u.x) + cx, 0.f); ay += fmaxf(bf2f(u.y) + cy, 0.f);
        az += fmaxf(bf2f(u.z) + cz, 0.f); aw += fmaxf(bf2f(u.w) + cw, 0.f);
    }
    ushort4 o;
    o.x = f2bf(ax); o.y = f2bf(ay); o.z = f2bf(az); o.w = f2bf(aw);
    ((ushort4*)z)[(size_t)node * 64 + l] = o;
}

// ---------------- MFMA GEMM (256->256), bf16 in; LN->bf16 out or fp32 out ----------------

template <bool DO_LN>
__global__ __launch_bounds__(256) void k_gemm_mfma(
    const unsigned short* __restrict__ zin, const unsigned short* __restrict__ Wt,
    const float* __restrict__ b, const float* __restrict__ g,
    const float* __restrict__ bt, void* __restrict__ xout_v, int n) {
    __shared__ unsigned short As[64 * 256];     // 32 KB, 512B/row swizzled
    __shared__ float psum[4][64], psq[4][64];
    __shared__ float mean_s[64], inv_s[64];

    int t = threadIdx.x;
    size_t node0 = (size_t)blockIdx.x * 64;

    // ---- stage bf16 tile ----
    const ushort4* zr = (const ushort4*)(zin + node0 * HDIM);
    #pragma unroll
    for (int i = 0; i < 16; i++) {
        int g4 = i * 256 + t;
        int row = g4 >> 6, c4 = g4 & 63;
        ushort4 v = make_ushort4(0, 0, 0, 0);
        if (node0 + row < (size_t)n) v = zr[g4];
        *(ushort4*)((char*)As + row * 512 + ((c4 << 3) ^ ((row & 7) << 4))) = v;
    }
    __syncthreads();

    int w  = t >> 6;
    int l  = t & 63;
    int lr = l & 15;
    int lk = l >> 4;

    f32x4 acc[4][4];
    #pragma unroll
    for (int rg = 0; rg < 4; rg++)
        #pragma unroll
        for (int cg = 0; cg < 4; cg++)
            acc[rg][cg] = (f32x4){0.f, 0.f, 0.f, 0.f};

    #pragma unroll
    for (int kt = 0; kt < 8; kt++) {
        int kbyte = kt * 64 + lk * 16;
        short8 a[4], bf[4];
        #pragma unroll
        for (int rg = 0; rg < 4; rg++) {
            int row = rg * 16 + lr;
            a[rg] = *(const short8*)((const char*)As + row * 512 + (kbyte ^ ((row & 7) << 4)));
        }
        #pragma unroll
        for (int cg = 0; cg < 4; cg++) {
            int coln = w * 64 + cg * 16 + lr;
            bf[cg] = *(const short8*)((const char*)Wt + coln * 512 + kbyte);
        }
        #pragma unroll
        for (int rg = 0; rg < 4; rg++)
            #pragma unroll
            for (int cg = 0; cg < 4; cg++)
                acc[rg][cg] = __builtin_amdgcn_mfma_f32_16x16x32_bf16(a[rg], bf[cg], acc[rg][cg], 0, 0, 0);
    }

    float bcol[4];
    #pragma unroll
    for (int cg = 0; cg < 4; cg++) bcol[cg] = b[w * 64 + cg * 16 + lr];
    #pragma unroll
    for (int rg = 0; rg < 4; rg++)
        #pragma unroll
        for (int cg = 0; cg < 4; cg++)
            #pragma unroll
            for (int j = 0; j < 4; j++) acc[rg][cg][j] += bcol[cg];

    if (!DO_LN) {
        float* xout = (float*)xout_v;
        #pragma unroll
        for (int rg = 0; rg < 4; rg++)
            #pragma unroll
            for (int j = 0; j < 4; j++) {
                int row = rg * 16 + lk * 4 + j;
                size_t node = node0 + row;
                if (node < (size_t)n) {
                    #pragma unroll
                    for (int cg = 0; cg < 4; cg++)
                        xout[node * HDIM + w * 64 + cg * 16 + lr] = acc[rg][cg][j];
                }
            }
        return;
    }

    // ---- fused LayerNorm ----
    float sv[4][4], sq[4][4];
    #pragma unroll
    for (int rg = 0; rg < 4; rg++)
        #pragma unroll
        for (int j = 0; j < 4; j++) {
            float s = 0.f, q = 0.f;
            #pragma unroll
            for (int cg = 0; cg < 4; cg++) {
                float v = acc[rg][cg][j];
                s += v; q += v * v;
            }
            sv[rg][j] = s; sq[rg][j] = q;
        }
    #pragma unroll
    for (int off = 1; off < 16; off <<= 1) {
        #pragma unroll
        for (int rg = 0; rg < 4; rg++)
            #pragma unroll
            for (int j = 0; j < 4; j++) {
                sv[rg][j] += __shfl_xor(sv[rg][j], off, 64);
                sq[rg][j] += __shfl_xor(sq[rg][j], off, 64);
            }
    }
    if (lr == 0) {
        #pragma unroll
        for (int rg = 0; rg < 4; rg++)
            #pragma unroll
            for (int j = 0; j < 4; j++) {
                int row = rg * 16 + lk * 4 + j;
                psum[w][row] = sv[rg][j];
                psq[w][row]  = sq[rg][j];
            }
    }
    __syncthreads();
    if (t < 64) {
        float s = psum[0][t] + psum[1][t] + psum[2][t] + psum[3][t];
        float q = psq[0][t] + psq[1][t] + psq[2][t] + psq[3][t];
        float m = s * (1.f / 256.f);
        float var = q * (1.f / 256.f) - m * m;
        mean_s[t] = m;
        inv_s[t]  = rsqrtf(var + 1e-5f);
    }
    __syncthreads();

    float gv[4], btv[4];
    #pragma unroll
    for (int cg = 0; cg < 4; cg++) {
        int coln = w * 64 + cg * 16 + lr;
        gv[cg] = g[coln]; btv[cg] = bt[coln];
    }
    // normalized bf16 into As (swizzled), then coalesced copy-out
    #pragma unroll
    for (int rg = 0; rg < 4; rg++)
        #pragma unroll
        for (int j = 0; j < 4; j++) {
            int row = rg * 16 + lk * 4 + j;
            float m = mean_s[row];
            float inv = inv_s[row];
            #pragma unroll
            for (int cg = 0; cg < 4; cg++) {
                int colI = w * 64 + cg * 16 + lr;
                float v = (acc[rg][cg][j] - m) * inv * gv[cg] + btv[cg];
                int byte = row * 512 + ((((colI >> 2) << 3) ^ ((row & 7) << 4)) + (colI & 3) * 2);
                *(unsigned short*)((char*)As + byte) = f2bf(v);
            }
        }
    __syncthreads();
    ushort4* xo = (ushort4*)((unsigned short*)xout_v + node0 * HDIM);
    #pragma unroll
    for (int i = 0; i < 16; i++) {
        int g4 = i * 256 + t;
        int row = g4 >> 6, c4 = g4 & 63;
        if (node0 + row < (size_t)n)
            xo[g4] = *(ushort4*)((char*)As + row * 512 + ((c4 << 3) ^ ((row & 7) << 4)));
    }
}

// ---------------- host ----------------

extern "C" void kernel_launch(void* const* d_in, const int* in_sizes, int n_in,
                              void* d_out, int out_size, void* d_ws, size_t ws_size,
                              hipStream_t stream) {
    const int*   atom = (const int*)d_in[0];
    const int*   src  = (const int*)d_in[1];
    const int*   dst  = (const int*)d_in[2];
    const float* eE   = (const float*)d_in[3];
    const float* eD   = (const float*)d_in[4];
    const float* eV   = (const float*)d_in[5];
    const float* eC   = (const float*)d_in[6];
    const float* eA   = (const float*)d_in[7];
    const float* eH   = (const float*)d_in[8];
    const float* eHy  = (const float*)d_in[9];
    const float* W0   = (const float*)d_in[10];
    const float* b0   = (const float*)d_in[11];
    const float* W1   = (const float*)d_in[12];
    const float* b1   = (const float*)d_in[13];

    const int N = in_sizes[0] / 7;
    const int E = in_sizes[1];
    const int twoE = 2 * E;

    // workspace carve (bf16 intermediates)
    unsigned short* xb = (unsigned short*)d_ws;          // N x 256 bf16
    unsigned short* z  = xb + (size_t)N * HDIM;          // N x 256 bf16
    int*   rp      = (int*)(z + (size_t)N * HDIM);       // N+1
    int*   cursor  = rp + (N + 1);
    int*   deg     = cursor + N;
    int*   col     = deg + N;                            // 2E
    int*   bsum    = col + twoE;                         // <=1024
    uintptr_t pw = (uintptr_t)(bsum + 1024);
    pw = (pw + 255) & ~(uintptr_t)255;
    unsigned short* Wt  = (unsigned short*)pw;           // 5 x 256 x 256 bf16
    unsigned short* Wt0 = Wt + (size_t)5 * 65536;        // 256 x 96 bf16

    const int nb = (N + 1023) / 1024;

    // CSR build
    k_zero_int<<<(N + 255) / 256, 256, 0, stream>>>(deg, N);
    k_hist<<<(E + 255) / 256, 256, 0, stream>>>(src, dst, E, deg);
    k_scan_partial<<<nb, 256, 0, stream>>>(deg, rp, bsum, N);
    k_scan_bsum<<<1, 256, 0, stream>>>(bsum, nb);
    k_scan_add<<<(N + 255) / 256, 256, 0, stream>>>(rp, cursor, bsum, N, twoE);
    k_fill<<<(E + 255) / 256, 256, 0, stream>>>(src, dst, E, cursor, col);

    // weight prep
    for (int L = 0; L < 4; L++) {
        const float* Wn = (const float*)d_in[14 + 6 * L + 0];
        k_prep_w<<<256, 256, 0, stream>>>(Wn, Wt + (size_t)L * 65536);
    }
    k_prep_w<<<256, 256, 0, stream>>>(W1, Wt + (size_t)4 * 65536);
    k_prep_w0<<<96, 256, 0, stream>>>(W0, Wt0);

    const int nblk64 = (N + 63) / 64;
    const int nblk4  = (N + 3) / 4;

    // embed + first GEMM -> xb (bf16)
    k_embed0<<<nblk64, 256, 0, stream>>>(atom, eE, eD, eV, eC, eA, eH, eHy,
                                         Wt0, b0, xb, N);

    // 4 GINE layers: aggregate xb -> z (bf16), GEMM+LN z -> xb (bf16, in place ok)
    for (int L = 0; L < 4; L++) {
        const float* bn = (const float*)d_in[14 + 6 * L + 1];
        const float* We = (const float*)d_in[14 + 6 * L + 2];
        const float* be = (const float*)d_in[14 + 6 * L + 3];
        const float* g  = (const float*)d_in[14 + 6 * L + 4];
        const float* bt = (const float*)d_in[14 + 6 * L + 5];
        k_aggregate<<<nblk4, 256, 0, stream>>>(xb, rp, col, We, be, z, N);
        k_gemm_mfma<true><<<nblk64, 256, 0, stream>>>(z, Wt + (size_t)L * 65536,
                                                      bn, g, bt, xb, N);
    }

    // final projection: xb (bf16) -> d_out (fp32)
    k_gemm_mfma<false><<<nblk64, 256, 0, stream>>>(xb, Wt + (size_t)4 * 65536,
                                                   b1, nullptr, nullptr, d_out, N);
}

// Round 5
// 973.778 us; speedup vs baseline: 2.1236x; 1.0913x over previous
//
#include <hip/hip_runtime.h>

#define HDIM 256

typedef __attribute__((ext_vector_type(8))) short short8;
typedef __attribute__((ext_vector_type(4))) float f32x4;

typedef const __attribute__((address_space(1))) unsigned int* gas_ptr;
typedef __attribute__((address_space(3))) unsigned int* las_ptr;

__device__ __forceinline__ unsigned short f2bf(float f) {
    unsigned int u = __float_as_uint(f);
    u += 0x7FFF + ((u >> 16) & 1);   // round-to-nearest-even
    return (unsigned short)(u >> 16);
}
__device__ __forceinline__ float bf2f(unsigned short u) {
    return __uint_as_float(((unsigned int)u) << 16);
}

// ---------------- CSR build ----------------

__global__ void k_zero_int(int* p, int n) {
    int i = blockIdx.x * blockDim.x + threadIdx.x;
    if (i < n) p[i] = 0;
}

__global__ void k_hist(const int* __restrict__ src, const int* __restrict__ dst,
                       int E, int* __restrict__ deg) {
    int e = blockIdx.x * blockDim.x + threadIdx.x;
    if (e >= E) return;
    atomicAdd(&deg[dst[e]], 1);
    atomicAdd(&deg[src[e]], 1);
}

__global__ void k_scan_partial(const int* __restrict__ deg, int* __restrict__ rp,
                               int* __restrict__ bsum, int n) {
    __shared__ int sd[256];
    int t = threadIdx.x;
    int base = blockIdx.x * 1024 + t * 4;
    int v[4]; int tsum = 0;
    #pragma unroll
    for (int k = 0; k < 4; k++) { v[k] = (base + k < n) ? deg[base + k] : 0; tsum += v[k]; }
    sd[t] = tsum; __syncthreads();
    for (int off = 1; off < 256; off <<= 1) {
        int x = (t >= off) ? sd[t - off] : 0;
        __syncthreads();
        sd[t] += x;
        __syncthreads();
    }
    int run = sd[t] - tsum;
    if (t == 255) bsum[blockIdx.x] = sd[255];
    #pragma unroll
    for (int k = 0; k < 4; k++) { if (base + k < n) rp[base + k] = run; run += v[k]; }
}

__global__ void k_scan_bsum(int* __restrict__ bsum, int nb) {
    __shared__ int sd[256];
    int t = threadIdx.x;
    int base = t * 4;
    int v[4]; int tsum = 0;
    #pragma unroll
    for (int k = 0; k < 4; k++) { v[k] = (base + k < nb) ? bsum[base + k] : 0; tsum += v[k]; }
    sd[t] = tsum; __syncthreads();
    for (int off = 1; off < 256; off <<= 1) {
        int x = (t >= off) ? sd[t - off] : 0;
        __syncthreads();
        sd[t] += x;
        __syncthreads();
    }
    int run = sd[t] - tsum;
    #pragma unroll
    for (int k = 0; k < 4; k++) { if (base + k < nb) bsum[base + k] = run; run += v[k]; }
}

__global__ void k_scan_add(int* __restrict__ rp, int* __restrict__ cursor,
                           const int* __restrict__ bsum, int n, int twoE) {
    int i = blockIdx.x * blockDim.x + threadIdx.x;
    if (i < n) {
        int v = rp[i] + bsum[i >> 10];
        rp[i] = v;
        cursor[i] = v;
    }
    if (i == 0) rp[n] = twoE;
}

__global__ void k_fill(const int* __restrict__ src, const int* __restrict__ dst,
                       int E, int* __restrict__ cursor, int* __restrict__ col) {
    int e = blockIdx.x * blockDim.x + threadIdx.x;
    if (e >= E) return;
    int s = src[e], d = dst[e];
    int p = atomicAdd(&cursor[d], 1); col[p] = s;
    int q = atomicAdd(&cursor[s], 1); col[q] = d;
}

// ---------------- weight prep ----------------

__global__ void k_prep_w(const float* __restrict__ W, unsigned short* __restrict__ Wt) {
    int k = blockIdx.x, nn = threadIdx.x;
    Wt[nn * 256 + k] = f2bf(W[k * 256 + nn]);
}

__global__ void k_prep_w0(const float* __restrict__ W0, unsigned short* __restrict__ Wt0) {
    int k = blockIdx.x, nn = threadIdx.x;
    Wt0[nn * 96 + k] = (k < 88) ? f2bf(W0[k * 256 + nn]) : 0;
}

// ---------------- embed + GEMM0 (88 -> 256), MFMA, bf16 out ----------------

__global__ __launch_bounds__(256) void k_embed0(
    const int* __restrict__ atom,
    const float* __restrict__ eE, const float* __restrict__ eD,
    const float* __restrict__ eV, const float* __restrict__ eC,
    const float* __restrict__ eA, const float* __restrict__ eH,
    const float* __restrict__ eHy,
    const unsigned short* __restrict__ Wt0, const float* __restrict__ b0,
    unsigned short* __restrict__ x, int n) {
    __shared__ __align__(128) unsigned short As[64 * 256];  // 32 KB
    int t = threadIdx.x;
    size_t node0 = (size_t)blockIdx.x * 64;

    {
        int row = t >> 2;
        int ks  = (t & 3) * 24;
        size_t node = node0 + row;
        int a0 = 0, a1 = 0, a2 = 0, a3 = 0, a4 = 0, a5 = 0, a6 = 0;
        bool ok = node < (size_t)n;
        if (ok) {
            const int* a = atom + node * 7;
            a0 = a[0]; a1 = a[1]; a2 = a[2]; a3 = a[3]; a4 = a[4]; a5 = a[5]; a6 = a[6];
        }
        #pragma unroll
        for (int kk = 0; kk < 24; kk++) {
            int k = ks + kk;
            float val = 0.f;
            if (ok) {
                if (k < 64)       val = eE[a0 * 64 + k];
                else if (k < 68)  val = eD[a1 * 4 + (k - 64)];
                else if (k < 72)  val = eV[(a2 + 1) * 4 + (k - 68)];
                else if (k < 76)  val = eC[a3 * 4 + (k - 72)];
                else if (k < 80)  val = eA[a4 * 4 + (k - 76)];
                else if (k < 84)  val = eH[a5 * 4 + (k - 80)];
                else if (k < 88)  val = eHy[a6 * 4 + (k - 84)];
            }
            int boff = (k * 2) ^ ((row & 7) << 4);
            *(unsigned short*)((char*)As + row * 256 + boff) = f2bf(val);
        }
    }
    __syncthreads();

    int w  = t >> 6;
    int l  = t & 63;
    int lr = l & 15;
    int lk = l >> 4;

    f32x4 acc[4][4];
    #pragma unroll
    for (int rg = 0; rg < 4; rg++)
        #pragma unroll
        for (int cg = 0; cg < 4; cg++)
            acc[rg][cg] = (f32x4){0.f, 0.f, 0.f, 0.f};

    #pragma unroll
    for (int kt = 0; kt < 3; kt++) {
        int kbyte = kt * 64 + lk * 16;
        short8 a[4], bf[4];
        #pragma unroll
        for (int rg = 0; rg < 4; rg++) {
            int row = rg * 16 + lr;
            a[rg] = *(const short8*)((const char*)As + row * 256 + (kbyte ^ ((row & 7) << 4)));
        }
        #pragma unroll
        for (int cg = 0; cg < 4; cg++) {
            int coln = w * 64 + cg * 16 + lr;
            bf[cg] = *(const short8*)((const char*)Wt0 + coln * 192 + kbyte);
        }
        #pragma unroll
        for (int rg = 0; rg < 4; rg++)
            #pragma unroll
            for (int cg = 0; cg < 4; cg++)
                acc[rg][cg] = __builtin_amdgcn_mfma_f32_16x16x32_bf16(a[rg], bf[cg], acc[rg][cg], 0, 0, 0);
    }

    float bcol[4];
    #pragma unroll
    for (int cg = 0; cg < 4; cg++) bcol[cg] = b0[w * 64 + cg * 16 + lr];

    __syncthreads();   // As reads done; reuse for bf16 repack (512B/row swizzled)
    #pragma unroll
    for (int rg = 0; rg < 4; rg++)
        #pragma unroll
        for (int j = 0; j < 4; j++) {
            int row = rg * 16 + lk * 4 + j;
            #pragma unroll
            for (int cg = 0; cg < 4; cg++) {
                int colI = w * 64 + cg * 16 + lr;
                int byte = row * 512 + ((((colI >> 2) << 3) ^ ((row & 7) << 4)) + (colI & 3) * 2);
                *(unsigned short*)((char*)As + byte) = f2bf(acc[rg][cg][j] + bcol[cg]);
            }
        }
    __syncthreads();
    ushort4* xo = (ushort4*)(x + node0 * HDIM);
    #pragma unroll
    for (int i = 0; i < 16; i++) {
        int g4 = i * 256 + t;
        int row = g4 >> 6, c4 = g4 & 63;
        if (node0 + row < (size_t)n)
            xo[g4] = *(ushort4*)((char*)As + row * 512 + ((c4 << 3) ^ ((row & 7) << 4)));
    }
}

// ---------------- gather + relu + segment-sum (bf16, half-wave ushort8) ----------------
// one wave per node; half h (lanes 32h..32h+31) processes edges p0+h, p0+h+2, ...
// lane chunk j = lane&31 owns cols [8j, 8j+8). Combine halves via shfl_xor(32).

__global__ __launch_bounds__(256) void k_aggregate(
    const unsigned short* __restrict__ x, const int* __restrict__ rp,
    const int* __restrict__ col, const float* __restrict__ We,
    const float* __restrict__ be, unsigned short* __restrict__ z, int n) {
    int wid = threadIdx.x >> 6;
    int l   = threadIdx.x & 63;
    int node = blockIdx.x * 4 + wid;
    if (node >= n) return;
    int h = l >> 5;
    int j = l & 31;
    const short8* x8 = (const short8*)x;     // 32 chunks per row

    float c[8];
    {
        float4 w0 = ((const float4*)We)[2 * j],     w1 = ((const float4*)We)[2 * j + 1];
        float4 e0 = ((const float4*)be)[2 * j],     e1 = ((const float4*)be)[2 * j + 1];
        c[0] = w0.x + e0.x; c[1] = w0.y + e0.y; c[2] = w0.z + e0.z; c[3] = w0.w + e0.w;
        c[4] = w1.x + e1.x; c[5] = w1.y + e1.y; c[6] = w1.z + e1.z; c[7] = w1.w + e1.w;
    }

    float acc[8];
    #pragma unroll
    for (int k = 0; k < 8; k++) acc[k] = 0.f;
    if (h == 0) {
        short8 s = x8[(size_t)node * 32 + j];
        #pragma unroll
        for (int k = 0; k < 8; k++) acc[k] = bf2f((unsigned short)s[k]);
    }

    int p0 = rp[node], p1 = rp[node + 1];
    int p = p0 + h;
    for (; p + 2 < p1; p += 4) {
        int s0 = col[p], s1 = col[p + 2];
        short8 u0 = x8[(size_t)s0 * 32 + j];
        short8 u1 = x8[(size_t)s1 * 32 + j];
        #pragma unroll
        for (int k = 0; k < 8; k++) acc[k] += fmaxf(bf2f((unsigned short)u0[k]) + c[k], 0.f);
        #pragma unroll
        for (int k = 0; k < 8; k++) acc[k] += fmaxf(bf2f((unsigned short)u1[k]) + c[k], 0.f);
    }
    for (; p < p1; p += 2) {
        int s0 = col[p];
        short8 u0 = x8[(size_t)s0 * 32 + j];
        #pragma unroll
        for (int k = 0; k < 8; k++) acc[k] += fmaxf(bf2f((unsigned short)u0[k]) + c[k], 0.f);
    }

    #pragma unroll
    for (int k = 0; k < 8; k++) acc[k] += __shfl_xor(acc[k], 32, 64);

    if (h == 0) {
        short8 o;
        #pragma unroll
        for (int k = 0; k < 8; k++) o[k] = (short)f2bf(acc[k]);
        ((short8*)z)[(size_t)node * 32 + j] = o;
    }
}

// ---------------- MFMA GEMM (256->256), bf16 in; LN->bf16 out or fp32 out ----------------
// A-tile staged via global_load_lds (16B) with pre-swizzled SOURCE addresses:
// LDS linear dest, src = row*512 + (chunk ^ ((row&7)<<4)) (involution).

template <bool DO_LN>
__global__ __launch_bounds__(256) void k_gemm_mfma(
    const unsigned short* __restrict__ zin, const unsigned short* __restrict__ Wt,
    const float* __restrict__ b, const float* __restrict__ g,
    const float* __restrict__ bt, void* __restrict__ xout_v, int n) {
    __shared__ __align__(128) unsigned short As[64 * 256];   // 32 KB, 512B/row swizzled
    __shared__ float psum[4][64], psq[4][64];
    __shared__ float mean_s[64], inv_s[64];

    int t = threadIdx.x;
    int w = t >> 6;
    int l = t & 63;
    size_t node0 = (size_t)blockIdx.x * 64;

    if (node0 + 64 <= (size_t)n) {
        // fast path: full tile, async global->LDS with swizzled source
        const char* ztile = (const char*)(zin + node0 * HDIM);
        #pragma unroll
        for (int it = 0; it < 8; it++) {
            int ldsbase = w * 8192 + it * 1024;
            int row = (ldsbase >> 9) + (l >> 5);
            int chunk = (l & 31) * 16;
            const char* src = ztile + row * 512 + (chunk ^ ((row & 7) << 4));
            __builtin_amdgcn_global_load_lds((gas_ptr)src,
                                             (las_ptr)((char*)As + ldsbase),
                                             16, 0, 0);
        }
    } else {
        const ushort4* zr = (const ushort4*)(zin + node0 * HDIM);
        #pragma unroll
        for (int i = 0; i < 16; i++) {
            int g4 = i * 256 + t;
            int row = g4 >> 6, c4 = g4 & 63;
            ushort4 v = make_ushort4(0, 0, 0, 0);
            if (node0 + row < (size_t)n) v = zr[g4];
            *(ushort4*)((char*)As + row * 512 + ((c4 << 3) ^ ((row & 7) << 4))) = v;
        }
    }
    __syncthreads();

    int lr = l & 15;
    int lk = l >> 4;

    f32x4 acc[4][4];
    #pragma unroll
    for (int rg = 0; rg < 4; rg++)
        #pragma unroll
        for (int cg = 0; cg < 4; cg++)
            acc[rg][cg] = (f32x4){0.f, 0.f, 0.f, 0.f};

    #pragma unroll
    for (int kt = 0; kt < 8; kt++) {
        int kbyte = kt * 64 + lk * 16;
        short8 a[4], bf[4];
        #pragma unroll
        for (int rg = 0; rg < 4; rg++) {
            int row = rg * 16 + lr;
            a[rg] = *(const short8*)((const char*)As + row * 512 + (kbyte ^ ((row & 7) << 4)));
        }
        #pragma unroll
        for (int cg = 0; cg < 4; cg++) {
            int coln = w * 64 + cg * 16 + lr;
            bf[cg] = *(const short8*)((const char*)Wt + coln * 512 + kbyte);
        }
        #pragma unroll
        for (int rg = 0; rg < 4; rg++)
            #pragma unroll
            for (int cg = 0; cg < 4; cg++)
                acc[rg][cg] = __builtin_amdgcn_mfma_f32_16x16x32_bf16(a[rg], bf[cg], acc[rg][cg], 0, 0, 0);
    }

    float bcol[4];
    #pragma unroll
    for (int cg = 0; cg < 4; cg++) bcol[cg] = b[w * 64 + cg * 16 + lr];
    #pragma unroll
    for (int rg = 0; rg < 4; rg++)
        #pragma unroll
        for (int cg = 0; cg < 4; cg++)
            #pragma unroll
            for (int j = 0; j < 4; j++) acc[rg][cg][j] += bcol[cg];

    if (!DO_LN) {
        float* xout = (float*)xout_v;
        #pragma unroll
        for (int rg = 0; rg < 4; rg++)
            #pragma unroll
            for (int j = 0; j < 4; j++) {
                int row = rg * 16 + lk * 4 + j;
                size_t node = node0 + row;
                if (node < (size_t)n) {
                    #pragma unroll
                    for (int cg = 0; cg < 4; cg++)
                        xout[node * HDIM + w * 64 + cg * 16 + lr] = acc[rg][cg][j];
                }
            }
        return;
    }

    // ---- fused LayerNorm ----
    float sv[4][4], sq[4][4];
    #pragma unroll
    for (int rg = 0; rg < 4; rg++)
        #pragma unroll
        for (int j = 0; j < 4; j++) {
            float s = 0.f, q = 0.f;
            #pragma unroll
            for (int cg = 0; cg < 4; cg++) {
                float v = acc[rg][cg][j];
                s += v; q += v * v;
            }
            sv[rg][j] = s; sq[rg][j] = q;
        }
    #pragma unroll
    for (int off = 1; off < 16; off <<= 1) {
        #pragma unroll
        for (int rg = 0; rg < 4; rg++)
            #pragma unroll
            for (int j = 0; j < 4; j++) {
                sv[rg][j] += __shfl_xor(sv[rg][j], off, 64);
                sq[rg][j] += __shfl_xor(sq[rg][j], off, 64);
            }
    }
    if (lr == 0) {
        #pragma unroll
        for (int rg = 0; rg < 4; rg++)
            #pragma unroll
            for (int j = 0; j < 4; j++) {
                int row = rg * 16 + lk * 4 + j;
                psum[w][row] = sv[rg][j];
                psq[w][row]  = sq[rg][j];
            }
    }
    __syncthreads();
    if (t < 64) {
        float s = psum[0][t] + psum[1][t] + psum[2][t] + psum[3][t];
        float q = psq[0][t] + psq[1][t] + psq[2][t] + psq[3][t];
        float m = s * (1.f / 256.f);
        float var = q * (1.f / 256.f) - m * m;
        mean_s[t] = m;
        inv_s[t]  = rsqrtf(var + 1e-5f);
    }
    __syncthreads();

    float gv[4], btv[4];
    #pragma unroll
    for (int cg = 0; cg < 4; cg++) {
        int coln = w * 64 + cg * 16 + lr;
        gv[cg] = g[coln]; btv[cg] = bt[coln];
    }
    // normalized bf16 into As (swizzled), then coalesced copy-out
    #pragma unroll
    for (int rg = 0; rg < 4; rg++)
        #pragma unroll
        for (int j = 0; j < 4; j++) {
            int row = rg * 16 + lk * 4 + j;
            float m = mean_s[row];
            float inv = inv_s[row];
            #pragma unroll
            for (int cg = 0; cg < 4; cg++) {
                int colI = w * 64 + cg * 16 + lr;
                float v = (acc[rg][cg][j] - m) * inv * gv[cg] + btv[cg];
                int byte = row * 512 + ((((colI >> 2) << 3) ^ ((row & 7) << 4)) + (colI & 3) * 2);
                *(unsigned short*)((char*)As + byte) = f2bf(v);
            }
        }
    __syncthreads();
    ushort4* xo = (ushort4*)((unsigned short*)xout_v + node0 * HDIM);
    #pragma unroll
    for (int i = 0; i < 16; i++) {
        int g4 = i * 256 + t;
        int row = g4 >> 6, c4 = g4 & 63;
        if (node0 + row < (size_t)n)
            xo[g4] = *(ushort4*)((char*)As + row * 512 + ((c4 << 3) ^ ((row & 7) << 4)));
    }
}

// ---------------- host ----------------

extern "C" void kernel_launch(void* const* d_in, const int* in_sizes, int n_in,
                              void* d_out, int out_size, void* d_ws, size_t ws_size,
                              hipStream_t stream) {
    const int*   atom = (const int*)d_in[0];
    const int*   src  = (const int*)d_in[1];
    const int*   dst  = (const int*)d_in[2];
    const float* eE   = (const float*)d_in[3];
    const float* eD   = (const float*)d_in[4];
    const float* eV   = (const float*)d_in[5];
    const float* eC   = (const float*)d_in[6];
    const float* eA   = (const float*)d_in[7];
    const float* eH   = (const float*)d_in[8];
    const float* eHy  = (const float*)d_in[9];
    const float* W0   = (const float*)d_in[10];
    const float* b0   = (const float*)d_in[11];
    const float* W1   = (const float*)d_in[12];
    const float* b1   = (const float*)d_in[13];

    const int N = in_sizes[0] / 7;
    const int E = in_sizes[1];
    const int twoE = 2 * E;

    // workspace carve (bf16 intermediates)
    unsigned short* xb = (unsigned short*)d_ws;          // N x 256 bf16
    unsigned short* z  = xb + (size_t)N * HDIM;          // N x 256 bf16
    int*   rp      = (int*)(z + (size_t)N * HDIM);       // N+1
    int*   cursor  = rp + (N + 1);
    int*   deg     = cursor + N;
    int*   col     = deg + N;                            // 2E
    int*   bsum    = col + twoE;                         // <=1024
    uintptr_t pw = (uintptr_t)(bsum + 1024);
    pw = (pw + 255) & ~(uintptr_t)255;
    unsigned short* Wt  = (unsigned short*)pw;           // 5 x 256 x 256 bf16
    unsigned short* Wt0 = Wt + (size_t)5 * 65536;        // 256 x 96 bf16

    const int nb = (N + 1023) / 1024;

    // CSR build
    k_zero_int<<<(N + 255) / 256, 256, 0, stream>>>(deg, N);
    k_hist<<<(E + 255) / 256, 256, 0, stream>>>(src, dst, E, deg);
    k_scan_partial<<<nb, 256, 0, stream>>>(deg, rp, bsum, N);
    k_scan_bsum<<<1, 256, 0, stream>>>(bsum, nb);
    k_scan_add<<<(N + 255) / 256, 256, 0, stream>>>(rp, cursor, bsum, N, twoE);
    k_fill<<<(E + 255) / 256, 256, 0, stream>>>(src, dst, E, cursor, col);

    // weight prep
    for (int L = 0; L < 4; L++) {
        const float* Wn = (const float*)d_in[14 + 6 * L + 0];
        k_prep_w<<<256, 256, 0, stream>>>(Wn, Wt + (size_t)L * 65536);
    }
    k_prep_w<<<256, 256, 0, stream>>>(W1, Wt + (size_t)4 * 65536);
    k_prep_w0<<<96, 256, 0, stream>>>(W0, Wt0);

    const int nblk64 = (N + 63) / 64;
    const int nblk4  = (N + 3) / 4;

    // embed + first GEMM -> xb (bf16)
    k_embed0<<<nblk64, 256, 0, stream>>>(atom, eE, eD, eV, eC, eA, eH, eHy,
                                         Wt0, b0, xb, N);

    // 4 GINE layers: aggregate xb -> z (bf16), GEMM+LN z -> xb (bf16)
    for (int L = 0; L < 4; L++) {
        const float* bn = (const float*)d_in[14 + 6 * L + 1];
        const float* We = (const float*)d_in[14 + 6 * L + 2];
        const float* be = (const float*)d_in[14 + 6 * L + 3];
        const float* g  = (const float*)d_in[14 + 6 * L + 4];
        const float* bt = (const float*)d_in[14 + 6 * L + 5];
        k_aggregate<<<nblk4, 256, 0, stream>>>(xb, rp, col, We, be, z, N);
        k_gemm_mfma<true><<<nblk64, 256, 0, stream>>>(z, Wt + (size_t)L * 65536,
                                                      bn, g, bt, xb, N);
    }

    // final projection: xb (bf16) -> d_out (fp32)
    k_gemm_mfma<false><<<nblk64, 256, 0, stream>>>(xb, Wt + (size_t)4 * 65536,
                                                   b1, nullptr, nullptr, d_out, N);
}

// Round 7
// 967.538 us; speedup vs baseline: 2.1373x; 1.0064x over previous
//
#include <hip/hip_runtime.h>

#define HDIM 256

typedef __attribute__((ext_vector_type(8))) short short8;
typedef __attribute__((ext_vector_type(4))) float f32x4;

typedef const __attribute__((address_space(1))) unsigned int* gas_ptr;
typedef __attribute__((address_space(3))) unsigned int* las_ptr;

__device__ __forceinline__ unsigned short f2bf(float f) {
    unsigned int u = __float_as_uint(f);
    u += 0x7FFF + ((u >> 16) & 1);   // round-to-nearest-even
    return (unsigned short)(u >> 16);
}
__device__ __forceinline__ float bf2f(unsigned short u) {
    return __uint_as_float(((unsigned int)u) << 16);
}

// ---------------- CSR build ----------------

__global__ void k_zero_int(int* p, int n) {
    int i = blockIdx.x * blockDim.x + threadIdx.x;
    if (i < n) p[i] = 0;
}

__global__ void k_hist(const int* __restrict__ src, const int* __restrict__ dst,
                       int E, int* __restrict__ deg) {
    int e = blockIdx.x * blockDim.x + threadIdx.x;
    if (e >= E) return;
    atomicAdd(&deg[dst[e]], 1);
    atomicAdd(&deg[src[e]], 1);
}

__global__ void k_scan_partial(const int* __restrict__ deg, int* __restrict__ rp,
                               int* __restrict__ bsum, int n) {
    __shared__ int sd[256];
    int t = threadIdx.x;
    int base = blockIdx.x * 1024 + t * 4;
    int v[4]; int tsum = 0;
    #pragma unroll
    for (int k = 0; k < 4; k++) { v[k] = (base + k < n) ? deg[base + k] : 0; tsum += v[k]; }
    sd[t] = tsum; __syncthreads();
    for (int off = 1; off < 256; off <<= 1) {
        int x = (t >= off) ? sd[t - off] : 0;
        __syncthreads();
        sd[t] += x;
        __syncthreads();
    }
    int run = sd[t] - tsum;
    if (t == 255) bsum[blockIdx.x] = sd[255];
    #pragma unroll
    for (int k = 0; k < 4; k++) { if (base + k < n) rp[base + k] = run; run += v[k]; }
}

__global__ void k_scan_bsum(int* __restrict__ bsum, int nb) {
    __shared__ int sd[256];
    int t = threadIdx.x;
    int base = t * 4;
    int v[4]; int tsum = 0;
    #pragma unroll
    for (int k = 0; k < 4; k++) { v[k] = (base + k < nb) ? bsum[base + k] : 0; tsum += v[k]; }
    sd[t] = tsum; __syncthreads();
    for (int off = 1; off < 256; off <<= 1) {
        int x = (t >= off) ? sd[t - off] : 0;
        __syncthreads();
        sd[t] += x;
        __syncthreads();
    }
    int run = sd[t] - tsum;
    #pragma unroll
    for (int k = 0; k < 4; k++) { if (base + k < nb) bsum[base + k] = run; run += v[k]; }
}

__global__ void k_scan_add(int* __restrict__ rp, int* __restrict__ cursor,
                           const int* __restrict__ bsum, int n, int twoE) {
    int i = blockIdx.x * blockDim.x + threadIdx.x;
    if (i < n) {
        int v = rp[i] + bsum[i >> 10];
        rp[i] = v;
        cursor[i] = v;
    }
    if (i == 0) rp[n] = twoE;
}

__global__ void k_fill(const int* __restrict__ src, const int* __restrict__ dst,
                       int E, int* __restrict__ cursor, int* __restrict__ col) {
    int e = blockIdx.x * blockDim.x + threadIdx.x;
    if (e >= E) return;
    int s = src[e], d = dst[e];
    int p = atomicAdd(&cursor[d], 1); col[p] = s;
    int q = atomicAdd(&cursor[s], 1); col[q] = d;
}

// ---------------- weight prep ----------------

__global__ void k_prep_w(const float* __restrict__ W, unsigned short* __restrict__ Wt) {
    int k = blockIdx.x, nn = threadIdx.x;
    Wt[nn * 256 + k] = f2bf(W[k * 256 + nn]);
}

__global__ void k_prep_w0(const float* __restrict__ W0, unsigned short* __restrict__ Wt0) {
    int k = blockIdx.x, nn = threadIdx.x;
    Wt0[nn * 96 + k] = (k < 88) ? f2bf(W0[k * 256 + nn]) : 0;
}

// ---------------- embed + GEMM0 (88 -> 256), MFMA, bf16 out ----------------

__global__ __launch_bounds__(256) void k_embed0(
    const int* __restrict__ atom,
    const float* __restrict__ eE, const float* __restrict__ eD,
    const float* __restrict__ eV, const float* __restrict__ eC,
    const float* __restrict__ eA, const float* __restrict__ eH,
    const float* __restrict__ eHy,
    const unsigned short* __restrict__ Wt0, const float* __restrict__ b0,
    unsigned short* __restrict__ x, int n) {
    __shared__ __align__(128) unsigned short As[64 * 256];  // 32 KB
    int t = threadIdx.x;
    size_t node0 = (size_t)blockIdx.x * 64;

    {
        int row = t >> 2;
        int ks  = (t & 3) * 24;
        size_t node = node0 + row;
        int a0 = 0, a1 = 0, a2 = 0, a3 = 0, a4 = 0, a5 = 0, a6 = 0;
        bool ok = node < (size_t)n;
        if (ok) {
            const int* a = atom + node * 7;
            a0 = a[0]; a1 = a[1]; a2 = a[2]; a3 = a[3]; a4 = a[4]; a5 = a[5]; a6 = a[6];
        }
        #pragma unroll
        for (int kk = 0; kk < 24; kk++) {
            int k = ks + kk;
            float val = 0.f;
            if (ok) {
                if (k < 64)       val = eE[a0 * 64 + k];
                else if (k < 68)  val = eD[a1 * 4 + (k - 64)];
                else if (k < 72)  val = eV[(a2 + 1) * 4 + (k - 68)];
                else if (k < 76)  val = eC[a3 * 4 + (k - 72)];
                else if (k < 80)  val = eA[a4 * 4 + (k - 76)];
                else if (k < 84)  val = eH[a5 * 4 + (k - 80)];
                else if (k < 88)  val = eHy[a6 * 4 + (k - 84)];
            }
            int boff = (k * 2) ^ ((row & 7) << 4);
            *(unsigned short*)((char*)As + row * 256 + boff) = f2bf(val);
        }
    }
    __syncthreads();

    int w  = t >> 6;
    int l  = t & 63;
    int lr = l & 15;
    int lk = l >> 4;

    f32x4 acc[4][4];
    #pragma unroll
    for (int rg = 0; rg < 4; rg++)
        #pragma unroll
        for (int cg = 0; cg < 4; cg++)
            acc[rg][cg] = (f32x4){0.f, 0.f, 0.f, 0.f};

    #pragma unroll
    for (int kt = 0; kt < 3; kt++) {
        int kbyte = kt * 64 + lk * 16;
        short8 a[4], bf[4];
        #pragma unroll
        for (int rg = 0; rg < 4; rg++) {
            int row = rg * 16 + lr;
            a[rg] = *(const short8*)((const char*)As + row * 256 + (kbyte ^ ((row & 7) << 4)));
        }
        #pragma unroll
        for (int cg = 0; cg < 4; cg++) {
            int coln = w * 64 + cg * 16 + lr;
            bf[cg] = *(const short8*)((const char*)Wt0 + coln * 192 + kbyte);
        }
        #pragma unroll
        for (int rg = 0; rg < 4; rg++)
            #pragma unroll
            for (int cg = 0; cg < 4; cg++)
                acc[rg][cg] = __builtin_amdgcn_mfma_f32_16x16x32_bf16(a[rg], bf[cg], acc[rg][cg], 0, 0, 0);
    }

    float bcol[4];
    #pragma unroll
    for (int cg = 0; cg < 4; cg++) bcol[cg] = b0[w * 64 + cg * 16 + lr];

    __syncthreads();   // As reads done; reuse for bf16 repack (512B/row swizzled)
    #pragma unroll
    for (int rg = 0; rg < 4; rg++)
        #pragma unroll
        for (int j = 0; j < 4; j++) {
            int row = rg * 16 + lk * 4 + j;
            #pragma unroll
            for (int cg = 0; cg < 4; cg++) {
                int colI = w * 64 + cg * 16 + lr;
                int byte = row * 512 + ((((colI >> 2) << 3) ^ ((row & 7) << 4)) + (colI & 3) * 2);
                *(unsigned short*)((char*)As + byte) = f2bf(acc[rg][cg][j] + bcol[cg]);
            }
        }
    __syncthreads();
    ushort4* xo = (ushort4*)(x + node0 * HDIM);
    #pragma unroll
    for (int i = 0; i < 16; i++) {
        int g4 = i * 256 + t;
        int row = g4 >> 6, c4 = g4 & 63;
        if (node0 + row < (size_t)n)
            xo[g4] = *(ushort4*)((char*)As + row * 512 + ((c4 << 3) ^ ((row & 7) << 4)));
    }
}

// ---------------- gather + relu + segment-sum (bf16, shfl-broadcast indices) ----------------
// one wave per node; half h (lanes 32h..) handles edges e = 2q+h.
// lane chunk j = lane&31 owns cols [8j,8j+8). Neighbor indices preloaded into
// lane registers (col[p0+l]) and broadcast via __shfl.
// ALL loop bounds are wave-uniform so every __shfl executes with 64 active lanes.

__global__ __launch_bounds__(256) void k_aggregate(
    const unsigned short* __restrict__ x, const int* __restrict__ rp,
    const int* __restrict__ col, const float* __restrict__ We,
    const float* __restrict__ be, unsigned short* __restrict__ z, int n) {
    int wid = threadIdx.x >> 6;
    int l   = threadIdx.x & 63;
    int node = blockIdx.x * 4 + wid;
    if (node >= n) return;          // wave-uniform (node depends only on wave id)
    int h = l >> 5;
    int j = l & 31;
    const short8* x8 = (const short8*)x;     // 32 chunks of 16B per row

    float c[8];
    {
        float4 w0 = ((const float4*)We)[2 * j],     w1 = ((const float4*)We)[2 * j + 1];
        float4 e0 = ((const float4*)be)[2 * j],     e1 = ((const float4*)be)[2 * j + 1];
        c[0] = w0.x + e0.x; c[1] = w0.y + e0.y; c[2] = w0.z + e0.z; c[3] = w0.w + e0.w;
        c[4] = w1.x + e1.x; c[5] = w1.y + e1.y; c[6] = w1.z + e1.z; c[7] = w1.w + e1.w;
    }

    int p0 = rp[node], p1 = rp[node + 1];
    int deg = p1 - p0;
    int dcap = deg < 64 ? deg : 64;
    int idx = (l < dcap) ? col[p0 + l] : 0;

    float acc[8];
    #pragma unroll
    for (int k = 0; k < 8; k++) acc[k] = 0.f;
    if (h == 0) {                   // half 0: self row + even edges (round-5 composition)
        short8 s = x8[(size_t)node * 32 + j];
        #pragma unroll
        for (int k = 0; k < 8; k++) acc[k] = bf2f((unsigned short)s[k]);
    }

    if (dcap <= 8) {
        // straight-line: uniform trip count 4; predicated adds
        #pragma unroll
        for (int q = 0; q < 4; q++) {
            int e = 2 * q + h;
            int s0 = __shfl(idx, e < dcap ? e : 0, 64);
            short8 u = x8[(size_t)s0 * 32 + j];
            if (e < dcap) {
                #pragma unroll
                for (int k = 0; k < 8; k++) acc[k] += fmaxf(bf2f((unsigned short)u[k]) + c[k], 0.f);
            }
        }
    } else {
        // uniform pair-loop: Q = ceil(dcap/2) identical for both halves
        int Q = (dcap + 1) >> 1;
        int q = 0;
        for (; q + 2 <= Q; q += 2) {
            int e0 = 2 * q + h;
            int e1 = 2 * (q + 1) + h;
            int s0 = __shfl(idx, e0 < dcap ? e0 : 0, 64);
            int s1 = __shfl(idx, e1 < dcap ? e1 : 0, 64);
            short8 u0 = x8[(size_t)s0 * 32 + j];
            short8 u1 = x8[(size_t)s1 * 32 + j];
            if (e0 < dcap) {
                #pragma unroll
                for (int k = 0; k < 8; k++) acc[k] += fmaxf(bf2f((unsigned short)u0[k]) + c[k], 0.f);
            }
            if (e1 < dcap) {
                #pragma unroll
                for (int k = 0; k < 8; k++) acc[k] += fmaxf(bf2f((unsigned short)u1[k]) + c[k], 0.f);
            }
        }
        for (; q < Q; q++) {
            int e = 2 * q + h;
            int s0 = __shfl(idx, e < dcap ? e : 0, 64);
            short8 u = x8[(size_t)s0 * 32 + j];
            if (e < dcap) {
                #pragma unroll
                for (int k = 0; k < 8; k++) acc[k] += fmaxf(bf2f((unsigned short)u[k]) + c[k], 0.f);
            }
        }
        // extreme-degree fallback (deg > 64): uniform p-loop, predicated col load
        for (int p = p0 + 64; p < p1; p += 2) {
            int pp = p + h;
            int s0 = col[pp < p1 ? pp : p1 - 1];
            short8 u = x8[(size_t)s0 * 32 + j];
            if (pp < p1) {
                #pragma unroll
                for (int k = 0; k < 8; k++) acc[k] += fmaxf(bf2f((unsigned short)u[k]) + c[k], 0.f);
            }
        }
    }

    #pragma unroll
    for (int k = 0; k < 8; k++) acc[k] += __shfl_xor(acc[k], 32, 64);

    if (h == 0) {
        short8 o;
        #pragma unroll
        for (int k = 0; k < 8; k++) o[k] = (short)f2bf(acc[k]);
        ((short8*)z)[(size_t)node * 32 + j] = o;
    }
}

// ---------------- MFMA GEMM (256->256), bf16 in; LN->bf16 out or fp32 out ----------------
// A-tile staged via global_load_lds (16B) with pre-swizzled SOURCE addresses:
// LDS linear dest, src = row*512 + (chunk ^ ((row&7)<<4)) (involution).

template <bool DO_LN>
__global__ __launch_bounds__(256) void k_gemm_mfma(
    const unsigned short* __restrict__ zin, const unsigned short* __restrict__ Wt,
    const float* __restrict__ b, const float* __restrict__ g,
    const float* __restrict__ bt, void* __restrict__ xout_v, int n) {
    __shared__ __align__(128) unsigned short As[64 * 256];   // 32 KB, 512B/row swizzled
    __shared__ float psum[4][64], psq[4][64];
    __shared__ float mean_s[64], inv_s[64];

    int t = threadIdx.x;
    int w = t >> 6;
    int l = t & 63;
    size_t node0 = (size_t)blockIdx.x * 64;

    if (node0 + 64 <= (size_t)n) {
        const char* ztile = (const char*)(zin + node0 * HDIM);
        #pragma unroll
        for (int it = 0; it < 8; it++) {
            int ldsbase = w * 8192 + it * 1024;
            int row = (ldsbase >> 9) + (l >> 5);
            int chunk = (l & 31) * 16;
            const char* src = ztile + row * 512 + (chunk ^ ((row & 7) << 4));
            __builtin_amdgcn_global_load_lds((gas_ptr)src,
                                             (las_ptr)((char*)As + ldsbase),
                                             16, 0, 0);
        }
    } else {
        const ushort4* zr = (const ushort4*)(zin + node0 * HDIM);
        #pragma unroll
        for (int i = 0; i < 16; i++) {
            int g4 = i * 256 + t;
            int row = g4 >> 6, c4 = g4 & 63;
            ushort4 v = make_ushort4(0, 0, 0, 0);
            if (node0 + row < (size_t)n) v = zr[g4];
            *(ushort4*)((char*)As + row * 512 + ((c4 << 3) ^ ((row & 7) << 4))) = v;
        }
    }
    __syncthreads();

    int lr = l & 15;
    int lk = l >> 4;

    f32x4 acc[4][4];
    #pragma unroll
    for (int rg = 0; rg < 4; rg++)
        #pragma unroll
        for (int cg = 0; cg < 4; cg++)
            acc[rg][cg] = (f32x4){0.f, 0.f, 0.f, 0.f};

    #pragma unroll
    for (int kt = 0; kt < 8; kt++) {
        int kbyte = kt * 64 + lk * 16;
        short8 a[4], bf[4];
        #pragma unroll
        for (int rg = 0; rg < 4; rg++) {
            int row = rg * 16 + lr;
            a[rg] = *(const short8*)((const char*)As + row * 512 + (kbyte ^ ((row & 7) << 4)));
        }
        #pragma unroll
        for (int cg = 0; cg < 4; cg++) {
            int coln = w * 64 + cg * 16 + lr;
            bf[cg] = *(const short8*)((const char*)Wt + coln * 512 + kbyte);
        }
        #pragma unroll
        for (int rg = 0; rg < 4; rg++)
            #pragma unroll
            for (int cg = 0; cg < 4; cg++)
                acc[rg][cg] = __builtin_amdgcn_mfma_f32_16x16x32_bf16(a[rg], bf[cg], acc[rg][cg], 0, 0, 0);
    }

    float bcol[4];
    #pragma unroll
    for (int cg = 0; cg < 4; cg++) bcol[cg] = b[w * 64 + cg * 16 + lr];
    #pragma unroll
    for (int rg = 0; rg < 4; rg++)
        #pragma unroll
        for (int cg = 0; cg < 4; cg++)
            #pragma unroll
            for (int j = 0; j < 4; j++) acc[rg][cg][j] += bcol[cg];

    if (!DO_LN) {
        float* xout = (float*)xout_v;
        #pragma unroll
        for (int rg = 0; rg < 4; rg++)
            #pragma unroll
            for (int j = 0; j < 4; j++) {
                int row = rg * 16 + lk * 4 + j;
                size_t node = node0 + row;
                if (node < (size_t)n) {
                    #pragma unroll
                    for (int cg = 0; cg < 4; cg++)
                        xout[node * HDIM + w * 64 + cg * 16 + lr] = acc[rg][cg][j];
                }
            }
        return;
    }

    // ---- fused LayerNorm ----
    float sv[4][4], sq[4][4];
    #pragma unroll
    for (int rg = 0; rg < 4; rg++)
        #pragma unroll
        for (int j = 0; j < 4; j++) {
            float s = 0.f, q = 0.f;
            #pragma unroll
            for (int cg = 0; cg < 4; cg++) {
                float v = acc[rg][cg][j];
                s += v; q += v * v;
            }
            sv[rg][j] = s; sq[rg][j] = q;
        }
    #pragma unroll
    for (int off = 1; off < 16; off <<= 1) {
        #pragma unroll
        for (int rg = 0; rg < 4; rg++)
            #pragma unroll
            for (int j = 0; j < 4; j++) {
                sv[rg][j] += __shfl_xor(sv[rg][j], off, 64);
                sq[rg][j] += __shfl_xor(sq[rg][j], off, 64);
            }
    }
    if (lr == 0) {
        #pragma unroll
        for (int rg = 0; rg < 4; rg++)
            #pragma unroll
            for (int j = 0; j < 4; j++) {
                int row = rg * 16 + lk * 4 + j;
                psum[w][row] = sv[rg][j];
                psq[w][row]  = sq[rg][j];
            }
    }
    __syncthreads();
    if (t < 64) {
        float s = psum[0][t] + psum[1][t] + psum[2][t] + psum[3][t];
        float q = psq[0][t] + psq[1][t] + psq[2][t] + psq[3][t];
        float m = s * (1.f / 256.f);
        float var = q * (1.f / 256.f) - m * m;
        mean_s[t] = m;
        inv_s[t]  = rsqrtf(var + 1e-5f);
    }
    __syncthreads();

    float gv[4], btv[4];
    #pragma unroll
    for (int cg = 0; cg < 4; cg++) {
        int coln = w * 64 + cg * 16 + lr;
        gv[cg] = g[coln]; btv[cg] = bt[coln];
    }
    // normalized bf16 into As (swizzled), then coalesced copy-out
    #pragma unroll
    for (int rg = 0; rg < 4; rg++)
        #pragma unroll
        for (int j = 0; j < 4; j++) {
            int row = rg * 16 + lk * 4 + j;
            float m = mean_s[row];
            float inv = inv_s[row];
            #pragma unroll
            for (int cg = 0; cg < 4; cg++) {
                int colI = w * 64 + cg * 16 + lr;
                float v = (acc[rg][cg][j] - m) * inv * gv[cg] + btv[cg];
                int byte = row * 512 + ((((colI >> 2) << 3) ^ ((row & 7) << 4)) + (colI & 3) * 2);
                *(unsigned short*)((char*)As + byte) = f2bf(v);
            }
        }
    __syncthreads();
    ushort4* xo = (ushort4*)((unsigned short*)xout_v + node0 * HDIM);
    #pragma unroll
    for (int i = 0; i < 16; i++) {
        int g4 = i * 256 + t;
        int row = g4 >> 6, c4 = g4 & 63;
        if (node0 + row < (size_t)n)
            xo[g4] = *(ushort4*)((char*)As + row * 512 + ((c4 << 3) ^ ((row & 7) << 4)));
    }
}

// ---------------- host ----------------

extern "C" void kernel_launch(void* const* d_in, const int* in_sizes, int n_in,
                              void* d_out, int out_size, void* d_ws, size_t ws_size,
                              hipStream_t stream) {
    const int*   atom = (const int*)d_in[0];
    const int*   src  = (const int*)d_in[1];
    const int*   dst  = (const int*)d_in[2];
    const float* eE   = (const float*)d_in[3];
    const float* eD   = (const float*)d_in[4];
    const float* eV   = (const float*)d_in[5];
    const float* eC   = (const float*)d_in[6];
    const float* eA   = (const float*)d_in[7];
    const float* eH   = (const float*)d_in[8];
    const float* eHy  = (const float*)d_in[9];
    const float* W0   = (const float*)d_in[10];
    const float* b0   = (const float*)d_in[11];
    const float* W1   = (const float*)d_in[12];
    const float* b1   = (const float*)d_in[13];

    const int N = in_sizes[0] / 7;
    const int E = in_sizes[1];
    const int twoE = 2 * E;

    // workspace carve (bf16 intermediates)
    unsigned short* xb = (unsigned short*)d_ws;          // N x 256 bf16
    unsigned short* z  = xb + (size_t)N * HDIM;          // N x 256 bf16
    int*   rp      = (int*)(z + (size_t)N * HDIM);       // N+1
    int*   cursor  = rp + (N + 1);
    int*   deg     = cursor + N;
    int*   col     = deg + N;                            // 2E
    int*   bsum    = col + twoE;                         // <=1024
    uintptr_t pw = (uintptr_t)(bsum + 1024);
    pw = (pw + 255) & ~(uintptr_t)255;
    unsigned short* Wt  = (unsigned short*)pw;           // 5 x 256 x 256 bf16
    unsigned short* Wt0 = Wt + (size_t)5 * 65536;        // 256 x 96 bf16

    const int nb = (N + 1023) / 1024;

    // CSR build
    k_zero_int<<<(N + 255) / 256, 256, 0, stream>>>(deg, N);
    k_hist<<<(E + 255) / 256, 256, 0, stream>>>(src, dst, E, deg);
    k_scan_partial<<<nb, 256, 0, stream>>>(deg, rp, bsum, N);
    k_scan_bsum<<<1, 256, 0, stream>>>(bsum, nb);
    k_scan_add<<<(N + 255) / 256, 256, 0, stream>>>(rp, cursor, bsum, N, twoE);
    k_fill<<<(E + 255) / 256, 256, 0, stream>>>(src, dst, E, cursor, col);

    // weight prep
    for (int L = 0; L < 4; L++) {
        const float* Wn = (const float*)d_in[14 + 6 * L + 0];
        k_prep_w<<<256, 256, 0, stream>>>(Wn, Wt + (size_t)L * 65536);
    }
    k_prep_w<<<256, 256, 0, stream>>>(W1, Wt + (size_t)4 * 65536);
    k_prep_w0<<<96, 256, 0, stream>>>(W0, Wt0);

    const int nblk64 = (N + 63) / 64;
    const int nblk4  = (N + 3) / 4;

    // embed + first GEMM -> xb (bf16)
    k_embed0<<<nblk64, 256, 0, stream>>>(atom, eE, eD, eV, eC, eA, eH, eHy,
                                         Wt0, b0, xb, N);

    // 4 GINE layers: aggregate xb -> z (bf16), GEMM+LN z -> xb (bf16)
    for (int L = 0; L < 4; L++) {
        const float* bn = (const float*)d_in[14 + 6 * L + 1];
        const float* We = (const float*)d_in[14 + 6 * L + 2];
        const float* be = (const float*)d_in[14 + 6 * L + 3];
        const float* g  = (const float*)d_in[14 + 6 * L + 4];
        const float* bt = (const float*)d_in[14 + 6 * L + 5];
        k_aggregate<<<nblk4, 256, 0, stream>>>(xb, rp, col, We, be, z, N);
        k_gemm_mfma<true><<<nblk64, 256, 0, stream>>>(z, Wt + (size_t)L * 65536,
                                                      bn, g, bt, xb, N);
    }

    // final projection: xb (bf16) -> d_out (fp32)
    k_gemm_mfma<false><<<nblk64, 256, 0, stream>>>(xb, Wt + (size_t)4 * 65536,
                                                   b1, nullptr, nullptr, d_out, N);
}

// Round 8
// 936.701 us; speedup vs baseline: 2.2077x; 1.0329x over previous
//
#include <hip/hip_runtime.h>

#define HDIM 256

typedef __attribute__((ext_vector_type(8))) short short8;
typedef __attribute__((ext_vector_type(4))) float f32x4;

typedef const __attribute__((address_space(1))) unsigned int* gas_ptr;
typedef __attribute__((address_space(3))) unsigned int* las_ptr;

__device__ __forceinline__ unsigned short f2bf(float f) {
    unsigned int u = __float_as_uint(f);
    u += 0x7FFF + ((u >> 16) & 1);   // round-to-nearest-even
    return (unsigned short)(u >> 16);
}
__device__ __forceinline__ float bf2f(unsigned short u) {
    return __uint_as_float(((unsigned int)u) << 16);
}

// ---------------- CSR build ----------------

__global__ void k_zero_int(int* p, int n) {
    int i = blockIdx.x * blockDim.x + threadIdx.x;
    if (i < n) p[i] = 0;
}

__global__ void k_hist(const int* __restrict__ src, const int* __restrict__ dst,
                       int E, int* __restrict__ deg) {
    int e = blockIdx.x * blockDim.x + threadIdx.x;
    if (e >= E) return;
    atomicAdd(&deg[dst[e]], 1);
    atomicAdd(&deg[src[e]], 1);
}

__global__ void k_scan_partial(const int* __restrict__ deg, int* __restrict__ rp,
                               int* __restrict__ bsum, int n) {
    __shared__ int sd[256];
    int t = threadIdx.x;
    int base = blockIdx.x * 1024 + t * 4;
    int v[4]; int tsum = 0;
    #pragma unroll
    for (int k = 0; k < 4; k++) { v[k] = (base + k < n) ? deg[base + k] : 0; tsum += v[k]; }
    sd[t] = tsum; __syncthreads();
    for (int off = 1; off < 256; off <<= 1) {
        int x = (t >= off) ? sd[t - off] : 0;
        __syncthreads();
        sd[t] += x;
        __syncthreads();
    }
    int run = sd[t] - tsum;
    if (t == 255) bsum[blockIdx.x] = sd[255];
    #pragma unroll
    for (int k = 0; k < 4; k++) { if (base + k < n) rp[base + k] = run; run += v[k]; }
}

__global__ void k_scan_bsum(int* __restrict__ bsum, int nb) {
    __shared__ int sd[256];
    int t = threadIdx.x;
    int base = t * 4;
    int v[4]; int tsum = 0;
    #pragma unroll
    for (int k = 0; k < 4; k++) { v[k] = (base + k < nb) ? bsum[base + k] : 0; tsum += v[k]; }
    sd[t] = tsum; __syncthreads();
    for (int off = 1; off < 256; off <<= 1) {
        int x = (t >= off) ? sd[t - off] : 0;
        __syncthreads();
        sd[t] += x;
        __syncthreads();
    }
    int run = sd[t] - tsum;
    #pragma unroll
    for (int k = 0; k < 4; k++) { if (base + k < nb) bsum[base + k] = run; run += v[k]; }
}

__global__ void k_scan_add(int* __restrict__ rp, int* __restrict__ cursor,
                           const int* __restrict__ bsum, int n, int twoE) {
    int i = blockIdx.x * blockDim.x + threadIdx.x;
    if (i < n) {
        int v = rp[i] + bsum[i >> 10];
        rp[i] = v;
        cursor[i] = v;
    }
    if (i == 0) rp[n] = twoE;
}

__global__ void k_fill(const int* __restrict__ src, const int* __restrict__ dst,
                       int E, int* __restrict__ cursor, int* __restrict__ col) {
    int e = blockIdx.x * blockDim.x + threadIdx.x;
    if (e >= E) return;
    int s = src[e], d = dst[e];
    int p = atomicAdd(&cursor[d], 1); col[p] = s;
    int q = atomicAdd(&cursor[s], 1); col[q] = d;
}

// ---------------- weight prep ----------------

__global__ void k_prep_w(const float* __restrict__ W, unsigned short* __restrict__ Wt) {
    int k = blockIdx.x, nn = threadIdx.x;
    Wt[nn * 256 + k] = f2bf(W[k * 256 + nn]);
}

__global__ void k_prep_w0(const float* __restrict__ W0, unsigned short* __restrict__ Wt0) {
    int k = blockIdx.x, nn = threadIdx.x;
    Wt0[nn * 96 + k] = (k < 88) ? f2bf(W0[k * 256 + nn]) : 0;
}

// ---------------- embed + GEMM0 (88 -> 256), MFMA, bf16 out ----------------

__global__ __launch_bounds__(256) void k_embed0(
    const int* __restrict__ atom,
    const float* __restrict__ eE, const float* __restrict__ eD,
    const float* __restrict__ eV, const float* __restrict__ eC,
    const float* __restrict__ eA, const float* __restrict__ eH,
    const float* __restrict__ eHy,
    const unsigned short* __restrict__ Wt0, const float* __restrict__ b0,
    unsigned short* __restrict__ x, int n) {
    __shared__ __align__(128) unsigned short As[64 * 256];  // 32 KB
    int t = threadIdx.x;
    size_t node0 = (size_t)blockIdx.x * 64;

    {
        int row = t >> 2;
        int ks  = (t & 3) * 24;
        size_t node = node0 + row;
        int a0 = 0, a1 = 0, a2 = 0, a3 = 0, a4 = 0, a5 = 0, a6 = 0;
        bool ok = node < (size_t)n;
        if (ok) {
            const int* a = atom + node * 7;
            a0 = a[0]; a1 = a[1]; a2 = a[2]; a3 = a[3]; a4 = a[4]; a5 = a[5]; a6 = a[6];
        }
        #pragma unroll
        for (int kk = 0; kk < 24; kk++) {
            int k = ks + kk;
            float val = 0.f;
            if (ok) {
                if (k < 64)       val = eE[a0 * 64 + k];
                else if (k < 68)  val = eD[a1 * 4 + (k - 64)];
                else if (k < 72)  val = eV[(a2 + 1) * 4 + (k - 68)];
                else if (k < 76)  val = eC[a3 * 4 + (k - 72)];
                else if (k < 80)  val = eA[a4 * 4 + (k - 76)];
                else if (k < 84)  val = eH[a5 * 4 + (k - 80)];
                else if (k < 88)  val = eHy[a6 * 4 + (k - 84)];
            }
            int boff = (k * 2) ^ ((row & 7) << 4);
            *(unsigned short*)((char*)As + row * 256 + boff) = f2bf(val);
        }
    }
    __syncthreads();

    int w  = t >> 6;
    int l  = t & 63;
    int lr = l & 15;
    int lk = l >> 4;

    f32x4 acc[4][4];
    #pragma unroll
    for (int rg = 0; rg < 4; rg++)
        #pragma unroll
        for (int cg = 0; cg < 4; cg++)
            acc[rg][cg] = (f32x4){0.f, 0.f, 0.f, 0.f};

    #pragma unroll
    for (int kt = 0; kt < 3; kt++) {
        int kbyte = kt * 64 + lk * 16;
        short8 a[4], bf[4];
        #pragma unroll
        for (int rg = 0; rg < 4; rg++) {
            int row = rg * 16 + lr;
            a[rg] = *(const short8*)((const char*)As + row * 256 + (kbyte ^ ((row & 7) << 4)));
        }
        #pragma unroll
        for (int cg = 0; cg < 4; cg++) {
            int coln = w * 64 + cg * 16 + lr;
            bf[cg] = *(const short8*)((const char*)Wt0 + coln * 192 + kbyte);
        }
        #pragma unroll
        for (int rg = 0; rg < 4; rg++)
            #pragma unroll
            for (int cg = 0; cg < 4; cg++)
                acc[rg][cg] = __builtin_amdgcn_mfma_f32_16x16x32_bf16(a[rg], bf[cg], acc[rg][cg], 0, 0, 0);
    }

    float bcol[4];
    #pragma unroll
    for (int cg = 0; cg < 4; cg++) bcol[cg] = b0[w * 64 + cg * 16 + lr];

    __syncthreads();   // As reads done; reuse for bf16 repack (512B/row swizzled)
    #pragma unroll
    for (int rg = 0; rg < 4; rg++)
        #pragma unroll
        for (int j = 0; j < 4; j++) {
            int row = rg * 16 + lk * 4 + j;
            #pragma unroll
            for (int cg = 0; cg < 4; cg++) {
                int colI = w * 64 + cg * 16 + lr;
                int byte = row * 512 + ((((colI >> 2) << 3) ^ ((row & 7) << 4)) + (colI & 3) * 2);
                *(unsigned short*)((char*)As + byte) = f2bf(acc[rg][cg][j] + bcol[cg]);
            }
        }
    __syncthreads();
    ushort4* xo = (ushort4*)(x + node0 * HDIM);
    #pragma unroll
    for (int i = 0; i < 16; i++) {
        int g4 = i * 256 + t;
        int row = g4 >> 6, c4 = g4 & 63;
        if (node0 + row < (size_t)n)
            xo[g4] = *(ushort4*)((char*)As + row * 512 + ((c4 << 3) ^ ((row & 7) << 4)));
    }
}

// ---------------- gather + relu + segment-sum (bf16, half-wave per node) ----------------
// half-wave h of wave wid handles node = blk*8 + wid*2 + h; its 32 lanes each own
// 16B (cols [8j,8j+8)), so one full 512B row per load issue. Indices batched 32 at
// a time into lane regs, broadcast via __shfl from within the SAME half (all control
// flow inside a half is j-independent -> whole half active at every shfl).

__global__ __launch_bounds__(256) void k_aggregate(
    const unsigned short* __restrict__ x, const int* __restrict__ rp,
    const int* __restrict__ col, const float* __restrict__ We,
    const float* __restrict__ be, unsigned short* __restrict__ z, int n) {
    int wid = threadIdx.x >> 6;
    int l   = threadIdx.x & 63;
    int h   = l >> 5;
    int j   = l & 31;
    int node = blockIdx.x * 8 + wid * 2 + h;
    bool ok = node < n;
    int nd = ok ? node : 0;
    const short8* x8 = (const short8*)x;     // 32 chunks of 16B per row

    float c[8];
    {
        float4 w0 = ((const float4*)We)[2 * j],     w1 = ((const float4*)We)[2 * j + 1];
        float4 e0 = ((const float4*)be)[2 * j],     e1 = ((const float4*)be)[2 * j + 1];
        c[0] = w0.x + e0.x; c[1] = w0.y + e0.y; c[2] = w0.z + e0.z; c[3] = w0.w + e0.w;
        c[4] = w1.x + e1.x; c[5] = w1.y + e1.y; c[6] = w1.z + e1.z; c[7] = w1.w + e1.w;
    }

    int p0 = rp[nd], p1 = rp[nd + 1];
    int deg = ok ? (p1 - p0) : 0;

    float acc[8];
    {
        short8 s = x8[(size_t)nd * 32 + j];
        #pragma unroll
        for (int k = 0; k < 8; k++) acc[k] = ok ? bf2f((unsigned short)s[k]) : 0.f;
    }

    for (int b = 0; b < deg; b += 32) {          // per-half loop (divergence safe)
        int m = deg - b; if (m > 32) m = 32;
        int idx = (j < m) ? col[p0 + b + j] : 0;
        int e = 0;
        for (; e + 2 <= m; e += 2) {
            int s0 = __shfl(idx, (h << 5) + e, 64);
            int s1 = __shfl(idx, (h << 5) + e + 1, 64);
            short8 u0 = x8[(size_t)s0 * 32 + j];
            short8 u1 = x8[(size_t)s1 * 32 + j];
            #pragma unroll
            for (int k = 0; k < 8; k++) acc[k] += fmaxf(bf2f((unsigned short)u0[k]) + c[k], 0.f);
            #pragma unroll
            for (int k = 0; k < 8; k++) acc[k] += fmaxf(bf2f((unsigned short)u1[k]) + c[k], 0.f);
        }
        if (e < m) {
            int s0 = __shfl(idx, (h << 5) + e, 64);
            short8 u0 = x8[(size_t)s0 * 32 + j];
            #pragma unroll
            for (int k = 0; k < 8; k++) acc[k] += fmaxf(bf2f((unsigned short)u0[k]) + c[k], 0.f);
        }
    }

    if (ok) {
        short8 o;
        #pragma unroll
        for (int k = 0; k < 8; k++) o[k] = (short)f2bf(acc[k]);
        ((short8*)z)[(size_t)nd * 32 + j] = o;
    }
}

// ---------------- MFMA GEMM (256->256), bf16 in; LN->bf16 out or fp32 out ----------------
// A-tile staged via global_load_lds (16B) with pre-swizzled SOURCE addresses:
// LDS linear dest, src = row*512 + (chunk ^ ((row&7)<<4)) (involution).

template <bool DO_LN>
__global__ __launch_bounds__(256) void k_gemm_mfma(
    const unsigned short* __restrict__ zin, const unsigned short* __restrict__ Wt,
    const float* __restrict__ b, const float* __restrict__ g,
    const float* __restrict__ bt, void* __restrict__ xout_v, int n) {
    __shared__ __align__(128) unsigned short As[64 * 256];   // 32 KB, 512B/row swizzled
    __shared__ float psum[4][64], psq[4][64];
    __shared__ float mean_s[64], inv_s[64];

    int t = threadIdx.x;
    int w = t >> 6;
    int l = t & 63;
    size_t node0 = (size_t)blockIdx.x * 64;

    if (node0 + 64 <= (size_t)n) {
        const char* ztile = (const char*)(zin + node0 * HDIM);
        #pragma unroll
        for (int it = 0; it < 8; it++) {
            int ldsbase = w * 8192 + it * 1024;
            int row = (ldsbase >> 9) + (l >> 5);
            int chunk = (l & 31) * 16;
            const char* src = ztile + row * 512 + (chunk ^ ((row & 7) << 4));
            __builtin_amdgcn_global_load_lds((gas_ptr)src,
                                             (las_ptr)((char*)As + ldsbase),
                                             16, 0, 0);
        }
    } else {
        const ushort4* zr = (const ushort4*)(zin + node0 * HDIM);
        #pragma unroll
        for (int i = 0; i < 16; i++) {
            int g4 = i * 256 + t;
            int row = g4 >> 6, c4 = g4 & 63;
            ushort4 v = make_ushort4(0, 0, 0, 0);
            if (node0 + row < (size_t)n) v = zr[g4];
            *(ushort4*)((char*)As + row * 512 + ((c4 << 3) ^ ((row & 7) << 4))) = v;
        }
    }
    __syncthreads();

    int lr = l & 15;
    int lk = l >> 4;

    f32x4 acc[4][4];
    #pragma unroll
    for (int rg = 0; rg < 4; rg++)
        #pragma unroll
        for (int cg = 0; cg < 4; cg++)
            acc[rg][cg] = (f32x4){0.f, 0.f, 0.f, 0.f};

    #pragma unroll
    for (int kt = 0; kt < 8; kt++) {
        int kbyte = kt * 64 + lk * 16;
        short8 a[4], bf[4];
        #pragma unroll
        for (int rg = 0; rg < 4; rg++) {
            int row = rg * 16 + lr;
            a[rg] = *(const short8*)((const char*)As + row * 512 + (kbyte ^ ((row & 7) << 4)));
        }
        #pragma unroll
        for (int cg = 0; cg < 4; cg++) {
            int coln = w * 64 + cg * 16 + lr;
            bf[cg] = *(const short8*)((const char*)Wt + coln * 512 + kbyte);
        }
        #pragma unroll
        for (int rg = 0; rg < 4; rg++)
            #pragma unroll
            for (int cg = 0; cg < 4; cg++)
                acc[rg][cg] = __builtin_amdgcn_mfma_f32_16x16x32_bf16(a[rg], bf[cg], acc[rg][cg], 0, 0, 0);
    }

    float bcol[4];
    #pragma unroll
    for (int cg = 0; cg < 4; cg++) bcol[cg] = b[w * 64 + cg * 16 + lr];
    #pragma unroll
    for (int rg = 0; rg < 4; rg++)
        #pragma unroll
        for (int cg = 0; cg < 4; cg++)
            #pragma unroll
            for (int j = 0; j < 4; j++) acc[rg][cg][j] += bcol[cg];

    if (!DO_LN) {
        float* xout = (float*)xout_v;
        #pragma unroll
        for (int rg = 0; rg < 4; rg++)
            #pragma unroll
            for (int j = 0; j < 4; j++) {
                int row = rg * 16 + lk * 4 + j;
                size_t node = node0 + row;
                if (node < (size_t)n) {
                    #pragma unroll
                    for (int cg = 0; cg < 4; cg++)
                        xout[node * HDIM + w * 64 + cg * 16 + lr] = acc[rg][cg][j];
                }
            }
        return;
    }

    // ---- fused LayerNorm ----
    float sv[4][4], sq[4][4];
    #pragma unroll
    for (int rg = 0; rg < 4; rg++)
        #pragma unroll
        for (int j = 0; j < 4; j++) {
            float s = 0.f, q = 0.f;
            #pragma unroll
            for (int cg = 0; cg < 4; cg++) {
                float v = acc[rg][cg][j];
                s += v; q += v * v;
            }
            sv[rg][j] = s; sq[rg][j] = q;
        }
    #pragma unroll
    for (int off = 1; off < 16; off <<= 1) {
        #pragma unroll
        for (int rg = 0; rg < 4; rg++)
            #pragma unroll
            for (int j = 0; j < 4; j++) {
                sv[rg][j] += __shfl_xor(sv[rg][j], off, 64);
                sq[rg][j] += __shfl_xor(sq[rg][j], off, 64);
            }
    }
    if (lr == 0) {
        #pragma unroll
        for (int rg = 0; rg < 4; rg++)
            #pragma unroll
            for (int j = 0; j < 4; j++) {
                int row = rg * 16 + lk * 4 + j;
                psum[w][row] = sv[rg][j];
                psq[w][row]  = sq[rg][j];
            }
    }
    __syncthreads();
    if (t < 64) {
        float s = psum[0][t] + psum[1][t] + psum[2][t] + psum[3][t];
        float q = psq[0][t] + psq[1][t] + psq[2][t] + psq[3][t];
        float m = s * (1.f / 256.f);
        float var = q * (1.f / 256.f) - m * m;
        mean_s[t] = m;
        inv_s[t]  = rsqrtf(var + 1e-5f);
    }
    __syncthreads();

    float gv[4], btv[4];
    #pragma unroll
    for (int cg = 0; cg < 4; cg++) {
        int coln = w * 64 + cg * 16 + lr;
        gv[cg] = g[coln]; btv[cg] = bt[coln];
    }
    // normalized bf16 into As (swizzled), then coalesced copy-out
    #pragma unroll
    for (int rg = 0; rg < 4; rg++)
        #pragma unroll
        for (int j = 0; j < 4; j++) {
            int row = rg * 16 + lk * 4 + j;
            float m = mean_s[row];
            float inv = inv_s[row];
            #pragma unroll
            for (int cg = 0; cg < 4; cg++) {
                int colI = w * 64 + cg * 16 + lr;
                float v = (acc[rg][cg][j] - m) * inv * gv[cg] + btv[cg];
                int byte = row * 512 + ((((colI >> 2) << 3) ^ ((row & 7) << 4)) + (colI & 3) * 2);
                *(unsigned short*)((char*)As + byte) = f2bf(v);
            }
        }
    __syncthreads();
    ushort4* xo = (ushort4*)((unsigned short*)xout_v + node0 * HDIM);
    #pragma unroll
    for (int i = 0; i < 16; i++) {
        int g4 = i * 256 + t;
        int row = g4 >> 6, c4 = g4 & 63;
        if (node0 + row < (size_t)n)
            xo[g4] = *(ushort4*)((char*)As + row * 512 + ((c4 << 3) ^ ((row & 7) << 4)));
    }
}

// ---------------- host ----------------

extern "C" void kernel_launch(void* const* d_in, const int* in_sizes, int n_in,
                              void* d_out, int out_size, void* d_ws, size_t ws_size,
                              hipStream_t stream) {
    const int*   atom = (const int*)d_in[0];
    const int*   src  = (const int*)d_in[1];
    const int*   dst  = (const int*)d_in[2];
    const float* eE   = (const float*)d_in[3];
    const float* eD   = (const float*)d_in[4];
    const float* eV   = (const float*)d_in[5];
    const float* eC   = (const float*)d_in[6];
    const float* eA   = (const float*)d_in[7];
    const float* eH   = (const float*)d_in[8];
    const float* eHy  = (const float*)d_in[9];
    const float* W0   = (const float*)d_in[10];
    const float* b0   = (const float*)d_in[11];
    const float* W1   = (const float*)d_in[12];
    const float* b1   = (const float*)d_in[13];

    const int N = in_sizes[0] / 7;
    const int E = in_sizes[1];
    const int twoE = 2 * E;

    // workspace carve (bf16 intermediates)
    unsigned short* xb = (unsigned short*)d_ws;          // N x 256 bf16
    unsigned short* z  = xb + (size_t)N * HDIM;          // N x 256 bf16
    int*   rp      = (int*)(z + (size_t)N * HDIM);       // N+1
    int*   cursor  = rp + (N + 1);
    int*   deg     = cursor + N;
    int*   col     = deg + N;                            // 2E
    int*   bsum    = col + twoE;                         // <=1024
    uintptr_t pw = (uintptr_t)(bsum + 1024);
    pw = (pw + 255) & ~(uintptr_t)255;
    unsigned short* Wt  = (unsigned short*)pw;           // 5 x 256 x 256 bf16
    unsigned short* Wt0 = Wt + (size_t)5 * 65536;        // 256 x 96 bf16

    const int nb = (N + 1023) / 1024;

    // CSR build
    k_zero_int<<<(N + 255) / 256, 256, 0, stream>>>(deg, N);
    k_hist<<<(E + 255) / 256, 256, 0, stream>>>(src, dst, E, deg);
    k_scan_partial<<<nb, 256, 0, stream>>>(deg, rp, bsum, N);
    k_scan_bsum<<<1, 256, 0, stream>>>(bsum, nb);
    k_scan_add<<<(N + 255) / 256, 256, 0, stream>>>(rp, cursor, bsum, N, twoE);
    k_fill<<<(E + 255) / 256, 256, 0, stream>>>(src, dst, E, cursor, col);

    // weight prep
    for (int L = 0; L < 4; L++) {
        const float* Wn = (const float*)d_in[14 + 6 * L + 0];
        k_prep_w<<<256, 256, 0, stream>>>(Wn, Wt + (size_t)L * 65536);
    }
    k_prep_w<<<256, 256, 0, stream>>>(W1, Wt + (size_t)4 * 65536);
    k_prep_w0<<<96, 256, 0, stream>>>(W0, Wt0);

    const int nblk64 = (N + 63) / 64;
    const int nblk8  = (N + 7) / 8;

    // embed + first GEMM -> xb (bf16)
    k_embed0<<<nblk64, 256, 0, stream>>>(atom, eE, eD, eV, eC, eA, eH, eHy,
                                         Wt0, b0, xb, N);

    // 4 GINE layers: aggregate xb -> z (bf16), GEMM+LN z -> xb (bf16)
    for (int L = 0; L < 4; L++) {
        const float* bn = (const float*)d_in[14 + 6 * L + 1];
        const float* We = (const float*)d_in[14 + 6 * L + 2];
        const float* be = (const float*)d_in[14 + 6 * L + 3];
        const float* g  = (const float*)d_in[14 + 6 * L + 4];
        const float* bt = (const float*)d_in[14 + 6 * L + 5];
        k_aggregate<<<nblk8, 256, 0, stream>>>(xb, rp, col, We, be, z, N);
        k_gemm_mfma<true><<<nblk64, 256, 0, stream>>>(z, Wt + (size_t)L * 65536,
                                                      bn, g, bt, xb, N);
    }

    // final projection: xb (bf16) -> d_out (fp32)
    k_gemm_mfma<false><<<nblk64, 256, 0, stream>>>(xb, Wt + (size_t)4 * 65536,
                                                   b1, nullptr, nullptr, d_out, N);
}

// Round 9
// 793.971 us; speedup vs baseline: 2.6045x; 1.1798x over previous
//
#include <hip/hip_runtime.h>

#define HDIM 256

typedef __attribute__((ext_vector_type(8))) short short8;
typedef __attribute__((ext_vector_type(4))) float f32x4;

typedef const __attribute__((address_space(1))) unsigned int* gas_ptr;
typedef __attribute__((address_space(3))) unsigned int* las_ptr;

__device__ __forceinline__ unsigned short f2bf(float f) {
    unsigned int u = __float_as_uint(f);
    u += 0x7FFF + ((u >> 16) & 1);   // round-to-nearest-even
    return (unsigned short)(u >> 16);
}
__device__ __forceinline__ float bf2f(unsigned short u) {
    return __uint_as_float(((unsigned int)u) << 16);
}

// ---------------- CSR build ----------------

__global__ void k_zero_int(int* p, int n) {
    int i = blockIdx.x * blockDim.x + threadIdx.x;
    if (i < n) p[i] = 0;
}

__global__ void k_hist(const int* __restrict__ src, const int* __restrict__ dst,
                       int E, int* __restrict__ deg) {
    int e = blockIdx.x * blockDim.x + threadIdx.x;
    if (e >= E) return;
    atomicAdd(&deg[dst[e]], 1);
    atomicAdd(&deg[src[e]], 1);
}

__global__ void k_scan_partial(const int* __restrict__ deg, int* __restrict__ rp,
                               int* __restrict__ bsum, int n) {
    __shared__ int sd[256];
    int t = threadIdx.x;
    int base = blockIdx.x * 1024 + t * 4;
    int v[4]; int tsum = 0;
    #pragma unroll
    for (int k = 0; k < 4; k++) { v[k] = (base + k < n) ? deg[base + k] : 0; tsum += v[k]; }
    sd[t] = tsum; __syncthreads();
    for (int off = 1; off < 256; off <<= 1) {
        int x = (t >= off) ? sd[t - off] : 0;
        __syncthreads();
        sd[t] += x;
        __syncthreads();
    }
    int run = sd[t] - tsum;
    if (t == 255) bsum[blockIdx.x] = sd[255];
    #pragma unroll
    for (int k = 0; k < 4; k++) { if (base + k < n) rp[base + k] = run; run += v[k]; }
}

__global__ void k_scan_bsum(int* __restrict__ bsum, int nb) {
    __shared__ int sd[256];
    int t = threadIdx.x;
    int base = t * 4;
    int v[4]; int tsum = 0;
    #pragma unroll
    for (int k = 0; k < 4; k++) { v[k] = (base + k < nb) ? bsum[base + k] : 0; tsum += v[k]; }
    sd[t] = tsum; __syncthreads();
    for (int off = 1; off < 256; off <<= 1) {
        int x = (t >= off) ? sd[t - off] : 0;
        __syncthreads();
        sd[t] += x;
        __syncthreads();
    }
    int run = sd[t] - tsum;
    #pragma unroll
    for (int k = 0; k < 4; k++) { if (base + k < nb) bsum[base + k] = run; run += v[k]; }
}

__global__ void k_scan_add(int* __restrict__ rp, int* __restrict__ cursor,
                           const int* __restrict__ bsum, int n, int twoE) {
    int i = blockIdx.x * blockDim.x + threadIdx.x;
    if (i < n) {
        int v = rp[i] + bsum[i >> 10];
        rp[i] = v;
        cursor[i] = v;
    }
    if (i == 0) rp[n] = twoE;
}

__global__ void k_fill(const int* __restrict__ src, const int* __restrict__ dst,
                       int E, int* __restrict__ cursor, int* __restrict__ col) {
    int e = blockIdx.x * blockDim.x + threadIdx.x;
    if (e >= E) return;
    int s = src[e], d = dst[e];
    int p = atomicAdd(&cursor[d], 1); col[p] = s;
    int q = atomicAdd(&cursor[s], 1); col[q] = d;
}

// ---------------- weight prep ----------------

__global__ void k_prep_w(const float* __restrict__ W, unsigned short* __restrict__ Wt) {
    int k = blockIdx.x, nn = threadIdx.x;
    Wt[nn * 256 + k] = f2bf(W[k * 256 + nn]);
}

__global__ void k_prep_w0(const float* __restrict__ W0, unsigned short* __restrict__ Wt0) {
    int k = blockIdx.x, nn = threadIdx.x;
    Wt0[nn * 96 + k] = (k < 88) ? f2bf(W0[k * 256 + nn]) : 0;
}

// ---------------- embed + GEMM0 (88 -> 256), MFMA, bf16 out ----------------

__global__ __launch_bounds__(256) void k_embed0(
    const int* __restrict__ atom,
    const float* __restrict__ eE, const float* __restrict__ eD,
    const float* __restrict__ eV, const float* __restrict__ eC,
    const float* __restrict__ eA, const float* __restrict__ eH,
    const float* __restrict__ eHy,
    const unsigned short* __restrict__ Wt0, const float* __restrict__ b0,
    unsigned short* __restrict__ x, int n) {
    __shared__ __align__(128) unsigned short As[64 * 256];  // 32 KB
    int t = threadIdx.x;
    size_t node0 = (size_t)blockIdx.x * 64;

    {
        int row = t >> 2;
        int ks  = (t & 3) * 24;
        size_t node = node0 + row;
        int a0 = 0, a1 = 0, a2 = 0, a3 = 0, a4 = 0, a5 = 0, a6 = 0;
        bool ok = node < (size_t)n;
        if (ok) {
            const int* a = atom + node * 7;
            a0 = a[0]; a1 = a[1]; a2 = a[2]; a3 = a[3]; a4 = a[4]; a5 = a[5]; a6 = a[6];
        }
        #pragma unroll
        for (int kk = 0; kk < 24; kk++) {
            int k = ks + kk;
            float val = 0.f;
            if (ok) {
                if (k < 64)       val = eE[a0 * 64 + k];
                else if (k < 68)  val = eD[a1 * 4 + (k - 64)];
                else if (k < 72)  val = eV[(a2 + 1) * 4 + (k - 68)];
                else if (k < 76)  val = eC[a3 * 4 + (k - 72)];
                else if (k < 80)  val = eA[a4 * 4 + (k - 76)];
                else if (k < 84)  val = eH[a5 * 4 + (k - 80)];
                else if (k < 88)  val = eHy[a6 * 4 + (k - 84)];
            }
            int boff = (k * 2) ^ ((row & 7) << 4);
            *(unsigned short*)((char*)As + row * 256 + boff) = f2bf(val);
        }
    }
    __syncthreads();

    int w  = t >> 6;
    int l  = t & 63;
    int lr = l & 15;
    int lk = l >> 4;

    f32x4 acc[4][4];
    #pragma unroll
    for (int rg = 0; rg < 4; rg++)
        #pragma unroll
        for (int cg = 0; cg < 4; cg++)
            acc[rg][cg] = (f32x4){0.f, 0.f, 0.f, 0.f};

    #pragma unroll
    for (int kt = 0; kt < 3; kt++) {
        int kbyte = kt * 64 + lk * 16;
        short8 a[4], bf[4];
        #pragma unroll
        for (int rg = 0; rg < 4; rg++) {
            int row = rg * 16 + lr;
            a[rg] = *(const short8*)((const char*)As + row * 256 + (kbyte ^ ((row & 7) << 4)));
        }
        #pragma unroll
        for (int cg = 0; cg < 4; cg++) {
            int coln = w * 64 + cg * 16 + lr;
            bf[cg] = *(const short8*)((const char*)Wt0 + coln * 192 + kbyte);
        }
        #pragma unroll
        for (int rg = 0; rg < 4; rg++)
            #pragma unroll
            for (int cg = 0; cg < 4; cg++)
                acc[rg][cg] = __builtin_amdgcn_mfma_f32_16x16x32_bf16(a[rg], bf[cg], acc[rg][cg], 0, 0, 0);
    }

    float bcol[4];
    #pragma unroll
    for (int cg = 0; cg < 4; cg++) bcol[cg] = b0[w * 64 + cg * 16 + lr];

    __syncthreads();   // As reads done; reuse for bf16 repack (512B/row swizzled)
    #pragma unroll
    for (int rg = 0; rg < 4; rg++)
        #pragma unroll
        for (int j = 0; j < 4; j++) {
            int row = rg * 16 + lk * 4 + j;
            #pragma unroll
            for (int cg = 0; cg < 4; cg++) {
                int colI = w * 64 + cg * 16 + lr;
                int byte = row * 512 + ((((colI >> 2) << 3) ^ ((row & 7) << 4)) + (colI & 3) * 2);
                *(unsigned short*)((char*)As + byte) = f2bf(acc[rg][cg][j] + bcol[cg]);
            }
        }
    __syncthreads();
    ushort4* xo = (ushort4*)(x + node0 * HDIM);
    #pragma unroll
    for (int i = 0; i < 16; i++) {
        int g4 = i * 256 + t;
        int row = g4 >> 6, c4 = g4 & 63;
        if (node0 + row < (size_t)n)
            xo[g4] = *(ushort4*)((char*)As + row * 512 + ((c4 << 3) ^ ((row & 7) << 4)));
    }
}

// ---------------- fused GINE layer: gather -> LDS -> MFMA -> LN -> bf16 out ----------------
// 512 threads, 64 nodes/block. Phase 1: half-wave hh = wid*2+h gathers nodes
// hh*4..hh*4+3 (lane j owns 16B col-chunk j), writes bf16 rows direct to swizzled
// LDS. Phase 2: swapped-operand MFMA (A=Wt[feature][k], B=node rows): D.row=feature,
// D.col=node. Wave wid covers features [32*wid,32*wid+32) x all 64 nodes.

__global__ __launch_bounds__(512) void k_gine(
    const unsigned short* __restrict__ x, const int* __restrict__ rp,
    const int* __restrict__ col, const float* __restrict__ We,
    const float* __restrict__ be, const unsigned short* __restrict__ Wt,
    const float* __restrict__ b, const float* __restrict__ g,
    const float* __restrict__ bt, unsigned short* __restrict__ xout, int n) {
    __shared__ __align__(128) unsigned short As[64 * 256];   // 32 KB, 512B/row swizzled
    __shared__ float psum[8][64], psq[8][64];
    __shared__ float mean_s[64], inv_s[64];

    int t = threadIdx.x;
    int wid = t >> 6;       // 0..7
    int l = t & 63;
    int h = l >> 5;
    int j = l & 31;
    size_t node0 = (size_t)blockIdx.x * 64;

    // ---- phase 1: gather + relu + sum, write rows to LDS ----
    {
        int hh = wid * 2 + h;                  // 0..15, each does 4 rows
        const short8* x8 = (const short8*)x;   // 32 chunks of 16B per row
        float c[8];
        {
            float4 w0 = ((const float4*)We)[2 * j], w1 = ((const float4*)We)[2 * j + 1];
            float4 e0 = ((const float4*)be)[2 * j], e1 = ((const float4*)be)[2 * j + 1];
            c[0] = w0.x + e0.x; c[1] = w0.y + e0.y; c[2] = w0.z + e0.z; c[3] = w0.w + e0.w;
            c[4] = w1.x + e1.x; c[5] = w1.y + e1.y; c[6] = w1.z + e1.z; c[7] = w1.w + e1.w;
        }
        for (int q = 0; q < 4; q++) {
            int row = hh * 4 + q;
            size_t node = node0 + row;
            bool ok = node < (size_t)n;
            int nd = ok ? (int)node : 0;
            int p0 = rp[nd], p1 = rp[nd + 1];
            int deg = ok ? (p1 - p0) : 0;

            float acc[8];
            short8 s = x8[(size_t)nd * 32 + j];
            #pragma unroll
            for (int k = 0; k < 8; k++) acc[k] = ok ? bf2f((unsigned short)s[k]) : 0.f;

            for (int bb = 0; bb < deg; bb += 32) {
                int m = deg - bb; if (m > 32) m = 32;
                int idx = (j < m) ? col[p0 + bb + j] : 0;
                int e = 0;
                for (; e + 2 <= m; e += 2) {
                    int s0 = __shfl(idx, (h << 5) + e, 64);
                    int s1 = __shfl(idx, (h << 5) + e + 1, 64);
                    short8 u0 = x8[(size_t)s0 * 32 + j];
                    short8 u1 = x8[(size_t)s1 * 32 + j];
                    #pragma unroll
                    for (int k = 0; k < 8; k++) acc[k] += fmaxf(bf2f((unsigned short)u0[k]) + c[k], 0.f);
                    #pragma unroll
                    for (int k = 0; k < 8; k++) acc[k] += fmaxf(bf2f((unsigned short)u1[k]) + c[k], 0.f);
                }
                if (e < m) {
                    int s0 = __shfl(idx, (h << 5) + e, 64);
                    short8 u0 = x8[(size_t)s0 * 32 + j];
                    #pragma unroll
                    for (int k = 0; k < 8; k++) acc[k] += fmaxf(bf2f((unsigned short)u0[k]) + c[k], 0.f);
                }
            }

            short8 o;
            #pragma unroll
            for (int k = 0; k < 8; k++) o[k] = (short)f2bf(acc[k]);
            *(short8*)((char*)As + row * 512 + ((j ^ (row & 7)) << 4)) = o;
        }
    }
    __syncthreads();

    // ---- phase 2: MFMA (A = Wt features, B = node rows) ----
    int lr = l & 15;
    int lk = l >> 4;

    f32x4 acc[2][4];        // [fg][ng]
    #pragma unroll
    for (int fg = 0; fg < 2; fg++)
        #pragma unroll
        for (int ng = 0; ng < 4; ng++)
            acc[fg][ng] = (f32x4){0.f, 0.f, 0.f, 0.f};

    #pragma unroll
    for (int kt = 0; kt < 8; kt++) {
        int kbyte = kt * 64 + lk * 16;
        short8 a[2], bfr[4];
        #pragma unroll
        for (int fg = 0; fg < 2; fg++) {
            int feat = wid * 32 + fg * 16 + lr;
            a[fg] = *(const short8*)((const char*)Wt + feat * 512 + kbyte);
        }
        #pragma unroll
        for (int ng = 0; ng < 4; ng++) {
            int row = ng * 16 + lr;
            bfr[ng] = *(const short8*)((const char*)As + row * 512 + (kbyte ^ ((row & 7) << 4)));
        }
        #pragma unroll
        for (int fg = 0; fg < 2; fg++)
            #pragma unroll
            for (int ng = 0; ng < 4; ng++)
                acc[fg][ng] = __builtin_amdgcn_mfma_f32_16x16x32_bf16(a[fg], bfr[ng], acc[fg][ng], 0, 0, 0);
    }

    // bias (features vary with jj -> float4 load)
    #pragma unroll
    for (int fg = 0; fg < 2; fg++) {
        float4 bv = *(const float4*)&b[wid * 32 + fg * 16 + 4 * lk];
        #pragma unroll
        for (int ng = 0; ng < 4; ng++) {
            acc[fg][ng][0] += bv.x; acc[fg][ng][1] += bv.y;
            acc[fg][ng][2] += bv.z; acc[fg][ng][3] += bv.w;
        }
    }

    // ---- LayerNorm: per node (col) sum over features ----
    float sv[4], sq[4];
    #pragma unroll
    for (int ng = 0; ng < 4; ng++) {
        float s = 0.f, q = 0.f;
        #pragma unroll
        for (int fg = 0; fg < 2; fg++)
            #pragma unroll
            for (int jj = 0; jj < 4; jj++) {
                float v = acc[fg][ng][jj];
                s += v; q += v * v;
            }
        sv[ng] = s; sq[ng] = q;
    }
    #pragma unroll
    for (int ng = 0; ng < 4; ng++) {
        sv[ng] += __shfl_xor(sv[ng], 16, 64);
        sq[ng] += __shfl_xor(sq[ng], 16, 64);
        sv[ng] += __shfl_xor(sv[ng], 32, 64);
        sq[ng] += __shfl_xor(sq[ng], 32, 64);
    }
    if (lk == 0) {
        #pragma unroll
        for (int ng = 0; ng < 4; ng++) {
            psum[wid][ng * 16 + lr] = sv[ng];
            psq[wid][ng * 16 + lr]  = sq[ng];
        }
    }
    __syncthreads();
    if (t < 64) {
        float s = 0.f, q = 0.f;
        #pragma unroll
        for (int wv = 0; wv < 8; wv++) { s += psum[wv][t]; q += psq[wv][t]; }
        float m = s * (1.f / 256.f);
        float var = q * (1.f / 256.f) - m * m;
        mean_s[t] = m;
        inv_s[t]  = rsqrtf(var + 1e-5f);
    }
    __syncthreads();

    // scale + pack bf16 pairs -> 8B LDS writes (swizzled), then coalesced out
    #pragma unroll
    for (int fg = 0; fg < 2; fg++) {
        int fbase = wid * 32 + fg * 16 + 4 * lk;
        float4 gv  = *(const float4*)&g[fbase];
        float4 btv = *(const float4*)&bt[fbase];
        #pragma unroll
        for (int ng = 0; ng < 4; ng++) {
            int row = ng * 16 + lr;
            float m = mean_s[row];
            float inv = inv_s[row];
            ushort4 h4;
            h4.x = f2bf((acc[fg][ng][0] - m) * inv * gv.x + btv.x);
            h4.y = f2bf((acc[fg][ng][1] - m) * inv * gv.y + btv.y);
            h4.z = f2bf((acc[fg][ng][2] - m) * inv * gv.z + btv.z);
            h4.w = f2bf((acc[fg][ng][3] - m) * inv * gv.w + btv.w);
            int byte = row * 512 + ((fbase * 2) ^ ((row & 7) << 4));
            *(ushort4*)((char*)As + byte) = h4;
        }
    }
    __syncthreads();
    #pragma unroll
    for (int i = 0; i < 4; i++) {
        int g16 = i * 512 + t;          // 16B-chunk index, 2048 total
        int row = g16 >> 5, ch = g16 & 31;
        if (node0 + row < (size_t)n) {
            short8 v = *(const short8*)((const char*)As + row * 512 + ((ch ^ (row & 7)) << 4));
            ((short8*)xout)[(node0 + row) * 32 + ch] = v;
        }
    }
}

// ---------------- plain MFMA GEMM (final projection, bf16 in, fp32 out) ----------------

__global__ __launch_bounds__(256) void k_gemm_final(
    const unsigned short* __restrict__ zin, const unsigned short* __restrict__ Wt,
    const float* __restrict__ b, float* __restrict__ xout, int n) {
    __shared__ __align__(128) unsigned short As[64 * 256];   // 32 KB, 512B/row swizzled

    int t = threadIdx.x;
    int w = t >> 6;
    int l = t & 63;
    size_t node0 = (size_t)blockIdx.x * 64;

    if (node0 + 64 <= (size_t)n) {
        const char* ztile = (const char*)(zin + node0 * HDIM);
        #pragma unroll
        for (int it = 0; it < 8; it++) {
            int ldsbase = w * 8192 + it * 1024;
            int row = (ldsbase >> 9) + (l >> 5);
            int chunk = (l & 31) * 16;
            const char* src = ztile + row * 512 + (chunk ^ ((row & 7) << 4));
            __builtin_amdgcn_global_load_lds((gas_ptr)src,
                                             (las_ptr)((char*)As + ldsbase),
                                             16, 0, 0);
        }
    } else {
        const ushort4* zr = (const ushort4*)(zin + node0 * HDIM);
        #pragma unroll
        for (int i = 0; i < 16; i++) {
            int g4 = i * 256 + t;
            int row = g4 >> 6, c4 = g4 & 63;
            ushort4 v = make_ushort4(0, 0, 0, 0);
            if (node0 + row < (size_t)n) v = zr[g4];
            *(ushort4*)((char*)As + row * 512 + ((c4 << 3) ^ ((row & 7) << 4))) = v;
        }
    }
    __syncthreads();

    int lr = l & 15;
    int lk = l >> 4;

    f32x4 acc[4][4];
    #pragma unroll
    for (int rg = 0; rg < 4; rg++)
        #pragma unroll
        for (int cg = 0; cg < 4; cg++)
            acc[rg][cg] = (f32x4){0.f, 0.f, 0.f, 0.f};

    #pragma unroll
    for (int kt = 0; kt < 8; kt++) {
        int kbyte = kt * 64 + lk * 16;
        short8 a[4], bf[4];
        #pragma unroll
        for (int rg = 0; rg < 4; rg++) {
            int row = rg * 16 + lr;
            a[rg] = *(const short8*)((const char*)As + row * 512 + (kbyte ^ ((row & 7) << 4)));
        }
        #pragma unroll
        for (int cg = 0; cg < 4; cg++) {
            int coln = w * 64 + cg * 16 + lr;
            bf[cg] = *(const short8*)((const char*)Wt + coln * 512 + kbyte);
        }
        #pragma unroll
        for (int rg = 0; rg < 4; rg++)
            #pragma unroll
            for (int cg = 0; cg < 4; cg++)
                acc[rg][cg] = __builtin_amdgcn_mfma_f32_16x16x32_bf16(a[rg], bf[cg], acc[rg][cg], 0, 0, 0);
    }

    float bcol[4];
    #pragma unroll
    for (int cg = 0; cg < 4; cg++) bcol[cg] = b[w * 64 + cg * 16 + lr];
    #pragma unroll
    for (int rg = 0; rg < 4; rg++)
        #pragma unroll
        for (int j = 0; j < 4; j++) {
            int row = rg * 16 + lk * 4 + j;
            size_t node = node0 + row;
            if (node < (size_t)n) {
                #pragma unroll
                for (int cg = 0; cg < 4; cg++)
                    xout[node * HDIM + w * 64 + cg * 16 + lr] = acc[rg][cg][j] + bcol[cg];
            }
        }
}

// ---------------- host ----------------

extern "C" void kernel_launch(void* const* d_in, const int* in_sizes, int n_in,
                              void* d_out, int out_size, void* d_ws, size_t ws_size,
                              hipStream_t stream) {
    const int*   atom = (const int*)d_in[0];
    const int*   src  = (const int*)d_in[1];
    const int*   dst  = (const int*)d_in[2];
    const float* eE   = (const float*)d_in[3];
    const float* eD   = (const float*)d_in[4];
    const float* eV   = (const float*)d_in[5];
    const float* eC   = (const float*)d_in[6];
    const float* eA   = (const float*)d_in[7];
    const float* eH   = (const float*)d_in[8];
    const float* eHy  = (const float*)d_in[9];
    const float* W0   = (const float*)d_in[10];
    const float* b0   = (const float*)d_in[11];
    const float* W1   = (const float*)d_in[12];
    const float* b1   = (const float*)d_in[13];

    const int N = in_sizes[0] / 7;
    const int E = in_sizes[1];
    const int twoE = 2 * E;

    // workspace carve (bf16 ping-pong buffers)
    unsigned short* xb = (unsigned short*)d_ws;          // N x 256 bf16
    unsigned short* z  = xb + (size_t)N * HDIM;          // N x 256 bf16
    int*   rp      = (int*)(z + (size_t)N * HDIM);       // N+1
    int*   cursor  = rp + (N + 1);
    int*   deg     = cursor + N;
    int*   col     = deg + N;                            // 2E
    int*   bsum    = col + twoE;                         // <=1024
    uintptr_t pw = (uintptr_t)(bsum + 1024);
    pw = (pw + 255) & ~(uintptr_t)255;
    unsigned short* Wt  = (unsigned short*)pw;           // 5 x 256 x 256 bf16
    unsigned short* Wt0 = Wt + (size_t)5 * 65536;        // 256 x 96 bf16

    const int nb = (N + 1023) / 1024;

    // CSR build
    k_zero_int<<<(N + 255) / 256, 256, 0, stream>>>(deg, N);
    k_hist<<<(E + 255) / 256, 256, 0, stream>>>(src, dst, E, deg);
    k_scan_partial<<<nb, 256, 0, stream>>>(deg, rp, bsum, N);
    k_scan_bsum<<<1, 256, 0, stream>>>(bsum, nb);
    k_scan_add<<<(N + 255) / 256, 256, 0, stream>>>(rp, cursor, bsum, N, twoE);
    k_fill<<<(E + 255) / 256, 256, 0, stream>>>(src, dst, E, cursor, col);

    // weight prep
    for (int L = 0; L < 4; L++) {
        const float* Wn = (const float*)d_in[14 + 6 * L + 0];
        k_prep_w<<<256, 256, 0, stream>>>(Wn, Wt + (size_t)L * 65536);
    }
    k_prep_w<<<256, 256, 0, stream>>>(W1, Wt + (size_t)4 * 65536);
    k_prep_w0<<<96, 256, 0, stream>>>(W0, Wt0);

    const int nblk64 = (N + 63) / 64;

    // embed + first GEMM -> xb (bf16)
    k_embed0<<<nblk64, 256, 0, stream>>>(atom, eE, eD, eV, eC, eA, eH, eHy,
                                         Wt0, b0, xb, N);

    // 4 fused GINE layers, ping-pong xb <-> z
    unsigned short* cur = xb;
    unsigned short* nxt = z;
    for (int L = 0; L < 4; L++) {
        const float* bn = (const float*)d_in[14 + 6 * L + 1];
        const float* We = (const float*)d_in[14 + 6 * L + 2];
        const float* be = (const float*)d_in[14 + 6 * L + 3];
        const float* gg = (const float*)d_in[14 + 6 * L + 4];
        const float* bt = (const float*)d_in[14 + 6 * L + 5];
        k_gine<<<nblk64, 512, 0, stream>>>(cur, rp, col, We, be,
                                           Wt + (size_t)L * 65536, bn, gg, bt, nxt, N);
        unsigned short* tmp = cur; cur = nxt; nxt = tmp;
    }

    // final projection: cur (== xb after 4 swaps) -> d_out (fp32)
    k_gemm_final<<<nblk64, 256, 0, stream>>>(cur, Wt + (size_t)4 * 65536,
                                             b1, (float*)d_out, N);
}